// Round 3
// baseline (1975.664 us; speedup 1.0000x reference)
//
#include <hip/hip_runtime.h>

// ---------------------------------------------------------------------------
// Talking-heads transformer, 4 layers, f32 in/out (bf16 MFMA compute inside),
// MI355X (gfx950). B=8 N=512 DIM=768 H=12 DH=64 MLP=3072 DEPTH=4 LS=0.1
// ws layout (60 MB):
//   xf  f32  [4096,768]   @ 0          (residual accumulator)
//   h   bf16 [4096,768]   @ 12582912   (LN out; later attention-o)
//   qkv bf16 [4096,2304]  @ 18874368
//   S   bf16 [48,512,512] @ 37748736   (attn scores chunk; later MLP mid)
// ---------------------------------------------------------------------------

#define LSCALE 0.1f

typedef __bf16 bf16;
typedef __bf16 bf16x8 __attribute__((ext_vector_type(8)));
typedef unsigned short ushort8 __attribute__((ext_vector_type(8)));
typedef float  f32x4  __attribute__((ext_vector_type(4)));

// async global->LDS, 16B/lane; LDS dest = wave-uniform base + lane*16B.
__device__ __forceinline__ void g2l16(const void* g, void* l) {
    __builtin_amdgcn_global_load_lds(
        (const __attribute__((address_space(1))) void*)g,
        (__attribute__((address_space(3))) void*)l, 16, 0, 0);
}

// ---------------------------------------------------------------------------
// Shared epilogue.  EPI 0: C_bf16 = acc*scale
//                   EPI 1: C_bf16 = gelu_tanh(acc + bias[col])
//                   EPI 2: C_f32 += scale*(acc + bias[col])
// C layout of mfma_f32_16x16x32_bf16: col = lane&15, row = (lane>>4)*4 + reg.
// ---------------------------------------------------------------------------
template<int EPI>
__device__ __forceinline__ void epilogue(
    f32x4 (&acc)[4][4], void* Cv, int ldc, long cb,
    int m0, int n0, int wr, int wc, int lr, int lq,
    int N, const float* bias, float scale)
{
#pragma unroll
    for (int ni = 0; ni < 4; ni++) {
        const int gc = n0 + wc + ni * 16 + lr;
        if (gc >= N) continue;                    // o-GEMM has N=64 < tile
        float bv = 0.f;
        if (EPI != 0) bv = bias[gc];
#pragma unroll
        for (int mi = 0; mi < 4; mi++) {
#pragma unroll
            for (int r = 0; r < 4; r++) {
                const int gr = m0 + wr + mi * 16 + lq * 4 + r;  // M%128==0
                const long idx = cb + (long)gr * ldc + gc;
                if (EPI == 0) {
                    ((bf16*)Cv)[idx] = (bf16)(acc[mi][ni][r] * scale);
                } else if (EPI == 1) {
                    float xx = acc[mi][ni][r] + bv;
                    float u  = 0.7978845608f * (xx + 0.044715f * xx * xx * xx);
                    float th = 1.f - 2.f / (__expf(2.f * u) + 1.f);
                    ((bf16*)Cv)[idx] = (bf16)(0.5f * xx * (1.f + th));
                } else {
                    float* p = (float*)Cv + idx;
                    *p += scale * (acc[mi][ni][r] + bv);
                }
            }
        }
    }
}

// ---------------------------------------------------------------------------
// GEMM (Bt form): C[M,N] = A[M,K] @ Bt[N,K]^T    (QK^T only; A,B bf16)
// batched via z: z1=z/zmod, z2=z%zmod.
// ---------------------------------------------------------------------------
template<int EPI>
__global__ __launch_bounds__(256, 2)
void gemm_bt(const bf16* __restrict__ A, int lda, long saz1, long saz2,
             const bf16* __restrict__ Bt, int ldb, long sbz1, long sbz2,
             void* __restrict__ Cv, int ldc, long scz1, long scz2,
             int M, int N, int K, int zmod,
             const float* __restrict__ bias, float scale)
{
    __shared__ __align__(16) bf16 As[128 * 32];
    __shared__ __align__(16) bf16 Bs[128 * 32];

    const int z  = blockIdx.z;
    const int z1 = z / zmod, z2 = z - z1 * zmod;
    const bf16* Ab = A  + saz1 * (long)z1 + saz2 * (long)z2;
    const bf16* Bb = Bt + sbz1 * (long)z1 + sbz2 * (long)z2;

    const int m0 = blockIdx.y * 128, n0 = blockIdx.x * 128;
    const int tid = threadIdx.x, w = tid >> 6, l = tid & 63;
    const int wr = (w >> 1) * 64, wc = (w & 1) * 64;
    const int lr = l & 15, lq = l >> 4;
    const int srow = l >> 2, scol8 = (l & 3) * 8;

    f32x4 acc[4][4];
#pragma unroll
    for (int i = 0; i < 4; i++)
#pragma unroll
        for (int j = 0; j < 4; j++)
#pragma unroll
            for (int r = 0; r < 4; r++) acc[i][j][r] = 0.f;

    bf16* Al = As + w * 1024;
    bf16* Bl = Bs + w * 1024;

    for (int k0 = 0; k0 < K; k0 += 32) {
        const bf16* Ag = Ab + (long)(m0 + w * 32) * lda + k0;
        const bf16* Bg = Bb + (long)(n0 + w * 32) * ldb + k0;
        g2l16(Ag + (long)srow * lda + scol8,        Al);
        g2l16(Ag + (long)(srow + 16) * lda + scol8, Al + 512);
        g2l16(Bg + (long)srow * ldb + scol8,        Bl);
        g2l16(Bg + (long)(srow + 16) * ldb + scol8, Bl + 512);
        __syncthreads();

        bf16x8 fa[4], fb[4];
#pragma unroll
        for (int i = 0; i < 4; i++)
            fa[i] = *(const bf16x8*)(As + (wr + i * 16 + lr) * 32 + lq * 8);
#pragma unroll
        for (int i = 0; i < 4; i++)
            fb[i] = *(const bf16x8*)(Bs + (wc + i * 16 + lr) * 32 + lq * 8);
#pragma unroll
        for (int mi = 0; mi < 4; mi++)
#pragma unroll
            for (int ni = 0; ni < 4; ni++)
                acc[mi][ni] = __builtin_amdgcn_mfma_f32_16x16x32_bf16(
                    fa[mi], fb[ni], acc[mi][ni], 0, 0, 0);
        __syncthreads();
    }

    epilogue<EPI>(acc, Cv, ldc, scz1 * (long)z1 + scz2 * (long)z2,
                  m0, n0, wr, wc, lr, lq, N, bias, scale);
}

// ---------------------------------------------------------------------------
// GEMM (Bn form): C[M,N] = A[M,K](bf16) @ B[K,N]
// BF32=1: B is f32 (weights) — staged with f32->bf16 convert.
// BF32=0: B is bf16 (v inside qkv).
// B tile 32k x 128n staged transposed in LDS: Bst[n][k], row stride 40 el
// (16B-aligned rows), k-group XOR-swizzled by (n>>3)&3 to spread banks.
// ---------------------------------------------------------------------------
template<int EPI, int BF32>
__global__ __launch_bounds__(256, 2)
void gemm_bn(const bf16* __restrict__ A, int lda, long saz1, long saz2,
             const void* __restrict__ Bv, int ldb, long sbz1, long sbz2,
             void* __restrict__ Cv, int ldc, long scz1, long scz2,
             int M, int N, int K, int zmod,
             const float* __restrict__ bias, float scale)
{
    __shared__ __align__(16) bf16 As[128 * 32];
    __shared__ __align__(16) bf16 Bst[128 * 40];

    const int z  = blockIdx.z;
    const int z1 = z / zmod, z2 = z - z1 * zmod;
    const bf16* Ab = A + saz1 * (long)z1 + saz2 * (long)z2;
    const long boff = sbz1 * (long)z1 + sbz2 * (long)z2;

    const int m0 = blockIdx.y * 128, n0 = blockIdx.x * 128;
    const int tid = threadIdx.x, w = tid >> 6, l = tid & 63;
    const int wr = (w >> 1) * 64, wc = (w & 1) * 64;
    const int lr = l & 15, lq = l >> 4;
    const int srow = l >> 2, scol8 = (l & 3) * 8;
    // B staging: thread covers k = {2kp, 2kp+1}, n = nq*8 .. nq*8+7
    const int kp = tid >> 4, nq = tid & 15;
    const int kcol = ((((kp >> 2) ^ (nq & 3)) << 3) | ((kp & 3) << 1));

    f32x4 acc[4][4];
#pragma unroll
    for (int i = 0; i < 4; i++)
#pragma unroll
        for (int j = 0; j < 4; j++)
#pragma unroll
            for (int r = 0; r < 4; r++) acc[i][j][r] = 0.f;

    bf16* Al = As + w * 1024;
    unsigned short* Bw = (unsigned short*)Bst;

    for (int k0 = 0; k0 < K; k0 += 32) {
        const bf16* Ag = Ab + (long)(m0 + w * 32) * lda + k0;
        g2l16(Ag + (long)srow * lda + scol8,        Al);
        g2l16(Ag + (long)(srow + 16) * lda + scol8, Al + 512);

        const long be = boff + (long)(k0 + 2 * kp) * ldb + n0 + nq * 8;
        if (BF32) {
            const float* Bg = (const float*)Bv + be;
            f32x4 a0 = *(const f32x4*)(Bg);
            f32x4 a1 = *(const f32x4*)(Bg + 4);
            f32x4 b0 = *(const f32x4*)(Bg + ldb);
            f32x4 b1 = *(const f32x4*)(Bg + ldb + 4);
            float r0[8] = {a0[0], a0[1], a0[2], a0[3], a1[0], a1[1], a1[2], a1[3]};
            float r1[8] = {b0[0], b0[1], b0[2], b0[3], b1[0], b1[1], b1[2], b1[3]};
#pragma unroll
            for (int j = 0; j < 8; j++) {
                union { unsigned u; bf16 v[2]; } p;
                p.v[0] = (bf16)r0[j];
                p.v[1] = (bf16)r1[j];
                *(unsigned*)(Bw + (nq * 8 + j) * 40 + kcol) = p.u;
            }
        } else {
            const bf16* Bg = (const bf16*)Bv + be;
            ushort8 u0 = *(const ushort8*)(Bg);
            ushort8 u1 = *(const ushort8*)(Bg + ldb);
#pragma unroll
            for (int j = 0; j < 8; j++) {
                unsigned p = (unsigned)u0[j] | ((unsigned)u1[j] << 16);
                *(unsigned*)(Bw + (nq * 8 + j) * 40 + kcol) = p;
            }
        }
        __syncthreads();

        bf16x8 fa[4], fb[4];
#pragma unroll
        for (int i = 0; i < 4; i++)
            fa[i] = *(const bf16x8*)(As + (wr + i * 16 + lr) * 32 + lq * 8);
#pragma unroll
        for (int i = 0; i < 4; i++) {
            const int n = wc + i * 16 + lr;
            fb[i] = *(const bf16x8*)(Bst + n * 40 + ((lq ^ ((n >> 3) & 3)) << 3));
        }
#pragma unroll
        for (int mi = 0; mi < 4; mi++)
#pragma unroll
            for (int ni = 0; ni < 4; ni++)
                acc[mi][ni] = __builtin_amdgcn_mfma_f32_16x16x32_bf16(
                    fa[mi], fb[ni], acc[mi][ni], 0, 0, 0);
        __syncthreads();
    }

    epilogue<EPI>(acc, Cv, ldc, scz1 * (long)z1 + scz2 * (long)z2,
                  m0, n0, wr, wc, lr, lq, N, bias, scale);
}

// ---------------------------------------------------------------------------
// LayerNorm (no bias): h = (x-mu)*rsqrt(var+eps)*gamma ; x f32, gamma f32,
// out bf16. one block per row of 768.
// ---------------------------------------------------------------------------
__global__ __launch_bounds__(256)
void ln_k(const float* __restrict__ xf, const float* __restrict__ gam,
          bf16* __restrict__ out)
{
    const int row = blockIdx.x, t = threadIdx.x;
    const float* xr = xf + (long)row * 768;
    float v0 = xr[t], v1 = xr[t + 256], v2 = xr[t + 512];
    float s  = v0 + v1 + v2;
    float ss = v0 * v0 + v1 * v1 + v2 * v2;
#pragma unroll
    for (int off = 32; off; off >>= 1) {
        s  += __shfl_xor(s, off);
        ss += __shfl_xor(ss, off);
    }
    __shared__ float ps[4], pss[4];
    const int wv = t >> 6, l = t & 63;
    if (l == 0) { ps[wv] = s; pss[wv] = ss; }
    __syncthreads();
    s  = ps[0] + ps[1] + ps[2] + ps[3];
    ss = pss[0] + pss[1] + pss[2] + pss[3];
    const float mu = s * (1.f / 768.f);
    const float rs = rsqrtf(ss * (1.f / 768.f) - mu * mu + 1e-5f);
    bf16* orow = out + (long)row * 768;
    orow[t]       = (bf16)((v0 - mu) * rs * gam[t]);
    orow[t + 256] = (bf16)((v1 - mu) * rs * gam[t + 256]);
    orow[t + 512] = (bf16)((v2 - mu) * rs * gam[t + 512]);
}

// ---------------------------------------------------------------------------
// talking-heads mix (pre) -> softmax -> mix (post), in place on S chunk
// [4,12,512,512]. one block per (b-in-chunk, i). mp/mq f32 [12,12].
// ---------------------------------------------------------------------------
__global__ __launch_bounds__(256)
void mixsm_k(bf16* __restrict__ S, const float* __restrict__ mp,
             const float* __restrict__ mq)
{
    __shared__ float raw[12][512];
    __shared__ float buf[12][512];
    __shared__ float mpl[12][12], mql[12][12];
    const int b = blockIdx.y, i = blockIdx.x, t = threadIdx.x;
    bf16* Sb = S + ((long)b * 12 * 512 + i) * 512;

#pragma unroll
    for (int h2 = 0; h2 < 12; h2++)
        for (int j = t; j < 512; j += 256)
            raw[h2][j] = (float)Sb[(long)h2 * 262144 + j];
    if (t < 144) {
        mpl[t / 12][t % 12] = mp[t];
        mql[t / 12][t % 12] = mq[t];
    }
    __syncthreads();

    for (int g = 0; g < 12; g++)
        for (int j = t; j < 512; j += 256) {
            float a = 0.f;
#pragma unroll
            for (int h2 = 0; h2 < 12; h2++) a += raw[h2][j] * mpl[h2][g];
            buf[g][j] = a;
        }
    __syncthreads();

    const int wv = t >> 6, l = t & 63;
    for (int g = wv; g < 12; g += 4) {
        float mx = -3.0e38f;
        for (int j = l; j < 512; j += 64) mx = fmaxf(mx, buf[g][j]);
#pragma unroll
        for (int off = 32; off; off >>= 1) mx = fmaxf(mx, __shfl_xor(mx, off));
        float sm = 0.f;
        for (int j = l; j < 512; j += 64) {
            float e = __expf(buf[g][j] - mx);
            buf[g][j] = e; sm += e;
        }
#pragma unroll
        for (int off = 32; off; off >>= 1) sm += __shfl_xor(sm, off);
        const float inv = 1.f / sm;
        for (int j = l; j < 512; j += 64) buf[g][j] *= inv;
    }
    __syncthreads();

    for (int g = 0; g < 12; g++)
        for (int j = t; j < 512; j += 256) {
            float a = 0.f;
#pragma unroll
            for (int h2 = 0; h2 < 12; h2++) a += buf[h2][j] * mql[h2][g];
            Sb[(long)g * 262144 + j] = (bf16)a;
        }
}

// ---------------------------------------------------------------------------
extern "C" void kernel_launch(void* const* d_in, const int* in_sizes, int n_in,
                              void* d_out, int out_size, void* d_ws, size_t ws_size,
                              hipStream_t stream)
{
    (void)in_sizes; (void)n_in; (void)out_size; (void)ws_size;
    const float* x   = (const float*)d_in[0];
    const float* ln1 = (const float*)d_in[1];
    const float* Wq  = (const float*)d_in[2];
    const float* Wkv = (const float*)d_in[3];
    const float* mp  = (const float*)d_in[4];
    const float* mq  = (const float*)d_in[5];
    const float* Wo  = (const float*)d_in[6];
    const float* bo  = (const float*)d_in[7];
    const float* ln2 = (const float*)d_in[8];
    const float* W1  = (const float*)d_in[9];
    const float* b1  = (const float*)d_in[10];
    const float* W2  = (const float*)d_in[11];
    const float* b2  = (const float*)d_in[12];

    char* ws = (char*)d_ws;
    float* xf  = (float*)(ws);               // [4096,768] f32
    bf16* h    = (bf16*)(ws + 12582912);     // [4096,768]; also attention-o
    bf16* qkv  = (bf16*)(ws + 18874368);     // [4096,2304]
    bf16* S    = (bf16*)(ws + 37748736);     // [48,512,512]; also MLP mid
    bf16* o    = h;
    bf16* mid  = S;

    // residual init: xf = x (f32 d2d copy)
    hipMemcpyAsync(xf, x, 4096 * 768 * sizeof(float),
                   hipMemcpyDeviceToDevice, stream);

    for (int L = 0; L < 4; L++) {
        // h = LN(x)*ln1 ; qkv = h @ [Wq | Wkv]
        ln_k<<<4096, 256, 0, stream>>>(xf, ln1 + L * 768, h);
        gemm_bn<0, 1><<<dim3(6, 32, 1), 256, 0, stream>>>(
            h, 768, 0, 0, Wq + (long)L * 589824, 768, 0, 0,
            qkv, 2304, 0, 0, 4096, 768, 768, 1, nullptr, 1.f);
        gemm_bn<0, 1><<<dim3(12, 32, 1), 256, 0, stream>>>(
            h, 768, 0, 0, Wkv + (long)L * 1179648, 1536, 0, 0,
            qkv + 768, 2304, 0, 0, 4096, 1536, 768, 1, nullptr, 1.f);

        // attention in 2 chunks of 4 batches (S = 25 MB)
        for (int c = 0; c < 2; c++) {
            const long qb = (long)c * 4718592;       // 4 batches of qkv rows
            // S[b,h] = 0.125 * q @ k^T
            gemm_bt<0><<<dim3(4, 4, 48), 256, 0, stream>>>(
                qkv + qb,       2304, 1179648, 64,
                qkv + 768 + qb, 2304, 1179648, 64,
                S,               512, 3145728, 262144,
                512, 512, 64, 12, nullptr, 0.125f);

            mixsm_k<<<dim3(512, 4), 256, 0, stream>>>(S, mp + L * 144, mq + L * 144);

            // o[b,:,g*64..] = attn[b,g] @ v[b,g]   (v bf16 inside qkv, [K,N])
            gemm_bn<0, 0><<<dim3(1, 4, 48), 256, 0, stream>>>(
                S,                512, 3145728, 262144,
                qkv + 1536 + qb, 2304, 1179648, 64,
                o + (long)c * 1572864, 768, 393216, 64,
                512, 64, 512, 12, nullptr, 1.f);
        }

        // x += LS*(o @ Wo + bo)
        gemm_bn<2, 1><<<dim3(6, 32, 1), 256, 0, stream>>>(
            o, 768, 0, 0, Wo + (long)L * 589824, 768, 0, 0,
            xf, 768, 0, 0, 4096, 768, 768, 1, bo + L * 768, LSCALE);

        // MLP
        ln_k<<<4096, 256, 0, stream>>>(xf, ln2 + L * 768, h);
        gemm_bn<1, 1><<<dim3(24, 32, 1), 256, 0, stream>>>(
            h, 768, 0, 0, W1 + (long)L * 2359296, 3072, 0, 0,
            mid, 3072, 0, 0, 4096, 3072, 768, 1, b1 + L * 3072, 1.f);
        gemm_bn<2, 1><<<dim3(6, 32, 1), 256, 0, stream>>>(
            mid, 3072, 0, 0, W2 + (long)L * 2359296, 768, 0, 0,
            xf, 768, 0, 0, 4096, 768, 3072, 1, b2 + L * 768, LSCALE);
    }

    // output: f32
    hipMemcpyAsync(d_out, xf, 4096 * 768 * sizeof(float),
                   hipMemcpyDeviceToDevice, stream);
}

// Round 4
// 1626.486 us; speedup vs baseline: 1.2147x; 1.2147x over previous
//
#include <hip/hip_runtime.h>

// ---------------------------------------------------------------------------
// Talking-heads transformer, 4 layers, f32 in/out (bf16 MFMA inside), gfx950.
// B=8 N=512 DIM=768 H=12 DH=64 MLP=3072 DEPTH=4 LS=0.1 EPS=1e-5
// ws layout (67.6 MB):
//   xf  f32  [4096,768]   @ 0          residual accumulator
//   h   bf16 [4096,768]   @ 12582912   LN out; later attention-o
//   qkv bf16 [4096,2304]  @ 18874368
//   S   bf16 [48,512,512] @ 37748736   attn scores chunk; later MLP mid
//   Wt  bf16 [<=2359296]  @ 62914560   per-weight transposed bf16 [N,K]
// ---------------------------------------------------------------------------

#define LSCALE 0.1f

typedef __bf16 bf16;
typedef __bf16 bf16x8 __attribute__((ext_vector_type(8)));
typedef unsigned short ushort8 __attribute__((ext_vector_type(8)));
typedef float  f32x4  __attribute__((ext_vector_type(4)));

// async global->LDS, 16B/lane; LDS dest = wave-uniform base + lane*16B.
__device__ __forceinline__ void g2l16(const void* g, void* l) {
    __builtin_amdgcn_global_load_lds(
        (const __attribute__((address_space(1))) void*)g,
        (__attribute__((address_space(3))) void*)l, 16, 0, 0);
}

// ---------------------------------------------------------------------------
// Epilogue. EPI 0: C_bf16 = acc*scale
//           EPI 1: C_bf16 = gelu_tanh(acc + bias[col])
//           EPI 3: atomicAdd(C_f32, scale*(acc + bias[col]))   (split-K)
// C layout of mfma_f32_16x16x32_bf16: col = lane&15, row = (lane>>4)*4 + reg.
// ---------------------------------------------------------------------------
template<int EPI>
__device__ __forceinline__ void epilogue(
    f32x4 (&acc)[4][4], void* Cv, int ldc, long cb,
    int m0, int n0, int wr, int wc, int lr, int lq,
    int N, const float* bias, float scale)
{
#pragma unroll
    for (int ni = 0; ni < 4; ni++) {
        const int gc = n0 + wc + ni * 16 + lr;
        if (gc >= N) continue;                    // o-GEMM has N=64 < tile
        float bv = 0.f;
        if (EPI != 0 && bias) bv = bias[gc];
#pragma unroll
        for (int mi = 0; mi < 4; mi++) {
#pragma unroll
            for (int r = 0; r < 4; r++) {
                const int gr = m0 + wr + mi * 16 + lq * 4 + r;  // M%128==0
                const long idx = cb + (long)gr * ldc + gc;
                if (EPI == 0) {
                    ((bf16*)Cv)[idx] = (bf16)(acc[mi][ni][r] * scale);
                } else if (EPI == 1) {
                    float xx = acc[mi][ni][r] + bv;
                    float u  = 0.7978845608f * (xx + 0.044715f * xx * xx * xx);
                    float th = 1.f - 2.f / (__expf(2.f * u) + 1.f);
                    ((bf16*)Cv)[idx] = (bf16)(0.5f * xx * (1.f + th));
                } else {
                    atomicAdd((float*)Cv + idx, scale * (acc[mi][ni][r] + bv));
                }
            }
        }
    }
}

// ---------------------------------------------------------------------------
// GEMM (Bt form): C[M,N] = A[M,K] @ Bt[N,K]^T   (A,Bt bf16, g2l16 staging)
// batched via z: z1=z/zmod, z2=z%zmod. split-K: zmod=nsplit, strides saz2/sbz2
// advance along k, scz2=0, bias applied by slice z2==0 only.
// ---------------------------------------------------------------------------
template<int EPI>
__global__ __launch_bounds__(256, 2)
void gemm_bt(const bf16* __restrict__ A, int lda, long saz1, long saz2,
             const bf16* __restrict__ Bt, int ldb, long sbz1, long sbz2,
             void* __restrict__ Cv, int ldc, long scz1, long scz2,
             int M, int N, int K, int zmod,
             const float* __restrict__ bias, float scale)
{
    __shared__ __align__(16) bf16 As[128 * 32];
    __shared__ __align__(16) bf16 Bs[128 * 32];

    const int z  = blockIdx.z;
    const int z1 = z / zmod, z2 = z - z1 * zmod;
    const bf16* Ab = A  + saz1 * (long)z1 + saz2 * (long)z2;
    const bf16* Bb = Bt + sbz1 * (long)z1 + sbz2 * (long)z2;
    const float* bp = (EPI == 3 && z2 != 0) ? nullptr : bias;

    const int m0 = blockIdx.y * 128, n0 = blockIdx.x * 128;
    const int tid = threadIdx.x, w = tid >> 6, l = tid & 63;
    const int wr = (w >> 1) * 64, wc = (w & 1) * 64;
    const int lr = l & 15, lq = l >> 4;
    const int srow = l >> 2, scol8 = (l & 3) * 8;

    f32x4 acc[4][4];
#pragma unroll
    for (int i = 0; i < 4; i++)
#pragma unroll
        for (int j = 0; j < 4; j++)
#pragma unroll
            for (int r = 0; r < 4; r++) acc[i][j][r] = 0.f;

    bf16* Al = As + w * 1024;
    bf16* Bl = Bs + w * 1024;

    for (int k0 = 0; k0 < K; k0 += 32) {
        const bf16* Ag = Ab + (long)(m0 + w * 32) * lda + k0;
        const bf16* Bg = Bb + (long)(n0 + w * 32) * ldb + k0;
        g2l16(Ag + (long)srow * lda + scol8,        Al);
        g2l16(Ag + (long)(srow + 16) * lda + scol8, Al + 512);
        g2l16(Bg + (long)srow * ldb + scol8,        Bl);
        g2l16(Bg + (long)(srow + 16) * ldb + scol8, Bl + 512);
        __syncthreads();

        bf16x8 fa[4], fb[4];
#pragma unroll
        for (int i = 0; i < 4; i++)
            fa[i] = *(const bf16x8*)(As + (wr + i * 16 + lr) * 32 + lq * 8);
#pragma unroll
        for (int i = 0; i < 4; i++)
            fb[i] = *(const bf16x8*)(Bs + (wc + i * 16 + lr) * 32 + lq * 8);
#pragma unroll
        for (int mi = 0; mi < 4; mi++)
#pragma unroll
            for (int ni = 0; ni < 4; ni++)
                acc[mi][ni] = __builtin_amdgcn_mfma_f32_16x16x32_bf16(
                    fa[mi], fb[ni], acc[mi][ni], 0, 0, 0);
        __syncthreads();
    }

    epilogue<EPI>(acc, Cv, ldc, scz1 * (long)z1 + scz2 * (long)z2,
                  m0, n0, wr, wc, lr, lq, N, bp, scale);
}

// ---------------------------------------------------------------------------
// GEMM (Bn form, bf16 B): C[M,N] = A[M,K] @ B[K,N]  (o-GEMM only: B = v)
// B tile staged transposed in LDS via registers, stride 40, XOR swizzle.
// ---------------------------------------------------------------------------
template<int EPI>
__global__ __launch_bounds__(256, 2)
void gemm_bn(const bf16* __restrict__ A, int lda, long saz1, long saz2,
             const bf16* __restrict__ B, int ldb, long sbz1, long sbz2,
             void* __restrict__ Cv, int ldc, long scz1, long scz2,
             int M, int N, int K, int zmod,
             const float* __restrict__ bias, float scale)
{
    __shared__ __align__(16) bf16 As[128 * 32];
    __shared__ __align__(16) bf16 Bst[128 * 40];

    const int z  = blockIdx.z;
    const int z1 = z / zmod, z2 = z - z1 * zmod;
    const bf16* Ab = A + saz1 * (long)z1 + saz2 * (long)z2;
    const bf16* Bb = B + sbz1 * (long)z1 + sbz2 * (long)z2;

    const int m0 = blockIdx.y * 128, n0 = blockIdx.x * 128;
    const int tid = threadIdx.x, w = tid >> 6, l = tid & 63;
    const int wr = (w >> 1) * 64, wc = (w & 1) * 64;
    const int lr = l & 15, lq = l >> 4;
    const int srow = l >> 2, scol8 = (l & 3) * 8;
    const int kp = tid >> 4, nq = tid & 15;
    const int kcol = ((((kp >> 2) ^ (nq & 3)) << 3) | ((kp & 3) << 1));

    f32x4 acc[4][4];
#pragma unroll
    for (int i = 0; i < 4; i++)
#pragma unroll
        for (int j = 0; j < 4; j++)
#pragma unroll
            for (int r = 0; r < 4; r++) acc[i][j][r] = 0.f;

    bf16* Al = As + w * 1024;
    unsigned short* Bw = (unsigned short*)Bst;

    for (int k0 = 0; k0 < K; k0 += 32) {
        const bf16* Ag = Ab + (long)(m0 + w * 32) * lda + k0;
        g2l16(Ag + (long)srow * lda + scol8,        Al);
        g2l16(Ag + (long)(srow + 16) * lda + scol8, Al + 512);

        const bf16* Bg = Bb + (long)(k0 + 2 * kp) * ldb + n0 + nq * 8;
        ushort8 u0 = *(const ushort8*)(Bg);
        ushort8 u1 = *(const ushort8*)(Bg + ldb);
#pragma unroll
        for (int j = 0; j < 8; j++) {
            unsigned p = (unsigned)u0[j] | ((unsigned)u1[j] << 16);
            *(unsigned*)(Bw + (nq * 8 + j) * 40 + kcol) = p;
        }
        __syncthreads();

        bf16x8 fa[4], fb[4];
#pragma unroll
        for (int i = 0; i < 4; i++)
            fa[i] = *(const bf16x8*)(As + (wr + i * 16 + lr) * 32 + lq * 8);
#pragma unroll
        for (int i = 0; i < 4; i++) {
            const int n = wc + i * 16 + lr;
            fb[i] = *(const bf16x8*)(Bst + n * 40 + ((lq ^ ((n >> 3) & 3)) << 3));
        }
#pragma unroll
        for (int mi = 0; mi < 4; mi++)
#pragma unroll
            for (int ni = 0; ni < 4; ni++)
                acc[mi][ni] = __builtin_amdgcn_mfma_f32_16x16x32_bf16(
                    fa[mi], fb[ni], acc[mi][ni], 0, 0, 0);
        __syncthreads();
    }

    epilogue<EPI>(acc, Cv, ldc, scz1 * (long)z1 + scz2 * (long)z2,
                  m0, n0, wr, wc, lr, lq, N, bias, scale);
}

// ---------------------------------------------------------------------------
// transpose+convert: in f32 [K,N] -> out bf16 [N,K].  32x32 tiles.
// ---------------------------------------------------------------------------
__global__ __launch_bounds__(256)
void tconv_k(const float* __restrict__ in, bf16* __restrict__ out,
             int K, int N)
{
    __shared__ float t[32][33];
    const int n0 = blockIdx.x * 32, k0 = blockIdx.y * 32;
    const int x = threadIdx.x, y = threadIdx.y;
#pragma unroll
    for (int yy = 0; yy < 4; yy++)
        t[y + yy * 8][x] = in[(long)(k0 + y + yy * 8) * N + n0 + x];
    __syncthreads();
#pragma unroll
    for (int yy = 0; yy < 4; yy++)
        out[(long)(n0 + y + yy * 8) * K + k0 + x] = (bf16)t[x][y + yy * 8];
}

// ---------------------------------------------------------------------------
// LayerNorm (no bias): h = (x-mu)*rsqrt(var+eps)*gamma ; x,gamma f32, out bf16.
// ---------------------------------------------------------------------------
__global__ __launch_bounds__(256)
void ln_k(const float* __restrict__ xf, const float* __restrict__ gam,
          bf16* __restrict__ out)
{
    const int row = blockIdx.x, t = threadIdx.x;
    const float* xr = xf + (long)row * 768;
    float v0 = xr[t], v1 = xr[t + 256], v2 = xr[t + 512];
    float s  = v0 + v1 + v2;
    float ss = v0 * v0 + v1 * v1 + v2 * v2;
#pragma unroll
    for (int off = 32; off; off >>= 1) {
        s  += __shfl_xor(s, off);
        ss += __shfl_xor(ss, off);
    }
    __shared__ float ps[4], pss[4];
    const int wv = t >> 6, l = t & 63;
    if (l == 0) { ps[wv] = s; pss[wv] = ss; }
    __syncthreads();
    s  = ps[0] + ps[1] + ps[2] + ps[3];
    ss = pss[0] + pss[1] + pss[2] + pss[3];
    const float mu = s * (1.f / 768.f);
    const float rs = rsqrtf(ss * (1.f / 768.f) - mu * mu + 1e-5f);
    bf16* orow = out + (long)row * 768;
    orow[t]       = (bf16)((v0 - mu) * rs * gam[t]);
    orow[t + 256] = (bf16)((v1 - mu) * rs * gam[t + 256]);
    orow[t + 512] = (bf16)((v2 - mu) * rs * gam[t + 512]);
}

// ---------------------------------------------------------------------------
// talking-heads mix (pre) -> softmax -> mix (post), in place on S chunk
// [4,12,512,512]. one block per (b-in-chunk, i). mp/mq f32 [12,12].
// ---------------------------------------------------------------------------
__global__ __launch_bounds__(256)
void mixsm_k(bf16* __restrict__ S, const float* __restrict__ mp,
             const float* __restrict__ mq)
{
    __shared__ float raw[12][512];
    __shared__ float buf[12][512];
    __shared__ float mpl[12][12], mql[12][12];
    const int b = blockIdx.y, i = blockIdx.x, t = threadIdx.x;
    bf16* Sb = S + ((long)b * 12 * 512 + i) * 512;

#pragma unroll
    for (int h2 = 0; h2 < 12; h2++)
        for (int j = t; j < 512; j += 256)
            raw[h2][j] = (float)Sb[(long)h2 * 262144 + j];
    if (t < 144) {
        mpl[t / 12][t % 12] = mp[t];
        mql[t / 12][t % 12] = mq[t];
    }
    __syncthreads();

    for (int g = 0; g < 12; g++)
        for (int j = t; j < 512; j += 256) {
            float a = 0.f;
#pragma unroll
            for (int h2 = 0; h2 < 12; h2++) a += raw[h2][j] * mpl[h2][g];
            buf[g][j] = a;
        }
    __syncthreads();

    const int wv = t >> 6, l = t & 63;
    for (int g = wv; g < 12; g += 4) {
        float mx = -3.0e38f;
        for (int j = l; j < 512; j += 64) mx = fmaxf(mx, buf[g][j]);
#pragma unroll
        for (int off = 32; off; off >>= 1) mx = fmaxf(mx, __shfl_xor(mx, off));
        float sm = 0.f;
        for (int j = l; j < 512; j += 64) {
            float e = __expf(buf[g][j] - mx);
            buf[g][j] = e; sm += e;
        }
#pragma unroll
        for (int off = 32; off; off >>= 1) sm += __shfl_xor(sm, off);
        const float inv = 1.f / sm;
        for (int j = l; j < 512; j += 64) buf[g][j] *= inv;
    }
    __syncthreads();

    for (int g = 0; g < 12; g++)
        for (int j = t; j < 512; j += 256) {
            float a = 0.f;
#pragma unroll
            for (int h2 = 0; h2 < 12; h2++) a += buf[h2][j] * mql[h2][g];
            Sb[(long)g * 262144 + j] = (bf16)a;
        }
}

// ---------------------------------------------------------------------------
extern "C" void kernel_launch(void* const* d_in, const int* in_sizes, int n_in,
                              void* d_out, int out_size, void* d_ws, size_t ws_size,
                              hipStream_t stream)
{
    (void)in_sizes; (void)n_in; (void)out_size; (void)ws_size;
    const float* x   = (const float*)d_in[0];
    const float* ln1 = (const float*)d_in[1];
    const float* Wq  = (const float*)d_in[2];
    const float* Wkv = (const float*)d_in[3];
    const float* mp  = (const float*)d_in[4];
    const float* mq  = (const float*)d_in[5];
    const float* Wo  = (const float*)d_in[6];
    const float* bo  = (const float*)d_in[7];
    const float* ln2 = (const float*)d_in[8];
    const float* W1  = (const float*)d_in[9];
    const float* b1  = (const float*)d_in[10];
    const float* W2  = (const float*)d_in[11];
    const float* b2  = (const float*)d_in[12];

    char* ws = (char*)d_ws;
    float* xf  = (float*)(ws);               // [4096,768] f32
    bf16* h    = (bf16*)(ws + 12582912);     // [4096,768]; also attention-o
    bf16* qkv  = (bf16*)(ws + 18874368);     // [4096,2304]
    bf16* S    = (bf16*)(ws + 37748736);     // [48,512,512]; also MLP mid
    bf16* Wt   = (bf16*)(ws + 62914560);     // <=2359296 el, transposed weight
    bf16* o    = h;
    bf16* mid  = S;

    const dim3 tb(32, 8);

    // residual init: xf = x
    hipMemcpyAsync(xf, x, 4096 * 768 * sizeof(float),
                   hipMemcpyDeviceToDevice, stream);

    for (int L = 0; L < 4; L++) {
        // Wqkvt [2304,768] = [Wq | Wkv]^T
        tconv_k<<<dim3(24, 24), tb, 0, stream>>>(Wq + (long)L * 589824, Wt, 768, 768);
        tconv_k<<<dim3(48, 24), tb, 0, stream>>>(Wkv + (long)L * 1179648, Wt + 589824, 768, 1536);

        // h = LN(x)*ln1 ; qkv = h @ Wqkv
        ln_k<<<4096, 256, 0, stream>>>(xf, ln1 + L * 768, h);
        gemm_bt<0><<<dim3(18, 32, 1), 256, 0, stream>>>(
            h, 768, 0, 0, Wt, 768, 0, 0,
            qkv, 2304, 0, 0, 4096, 2304, 768, 1, nullptr, 1.f);

        // attention in 2 chunks of 4 batches (S = 25 MB)
        for (int c = 0; c < 2; c++) {
            const long qb = (long)c * 4718592;       // 4 batches of qkv rows
            // S[b,h] = 0.125 * q @ k^T
            gemm_bt<0><<<dim3(4, 4, 48), 256, 0, stream>>>(
                qkv + qb,       2304, 1179648, 64,
                qkv + 768 + qb, 2304, 1179648, 64,
                S,               512, 3145728, 262144,
                512, 512, 64, 12, nullptr, 0.125f);

            mixsm_k<<<dim3(512, 4), 256, 0, stream>>>(S, mp + L * 144, mq + L * 144);

            // o[b,:,g*64..] = attn[b,g] @ v[b,g]   (v bf16 inside qkv, [K,N])
            gemm_bn<0><<<dim3(1, 4, 48), 256, 0, stream>>>(
                S,                512, 3145728, 262144,
                qkv + 1536 + qb, 2304, 1179648, 64,
                o + (long)c * 1572864, 768, 393216, 64,
                512, 64, 512, 12, nullptr, 1.f);
        }

        // x += LS*(o @ Wo + bo)   (split-K x2)
        tconv_k<<<dim3(24, 24), tb, 0, stream>>>(Wo + (long)L * 589824, Wt, 768, 768);
        gemm_bt<3><<<dim3(6, 32, 2), 256, 0, stream>>>(
            o, 768, 0, 384, Wt, 768, 0, 384,
            xf, 768, 0, 0, 4096, 768, 384, 2, bo + L * 768, LSCALE);

        // MLP
        ln_k<<<4096, 256, 0, stream>>>(xf, ln2 + L * 768, h);
        tconv_k<<<dim3(96, 24), tb, 0, stream>>>(W1 + (long)L * 2359296, Wt, 768, 3072);
        gemm_bt<1><<<dim3(24, 32, 1), 256, 0, stream>>>(
            h, 768, 0, 0, Wt, 768, 0, 0,
            mid, 3072, 0, 0, 4096, 3072, 768, 1, b1 + L * 3072, 1.f);
        tconv_k<<<dim3(24, 96), tb, 0, stream>>>(W2 + (long)L * 2359296, Wt, 3072, 768);
        gemm_bt<3><<<dim3(6, 32, 4), 256, 0, stream>>>(
            mid, 3072, 0, 768, Wt, 3072, 0, 768,
            xf, 768, 0, 0, 4096, 768, 768, 4, b2 + L * 768, LSCALE);
    }

    // output: f32
    hipMemcpyAsync(d_out, xf, 4096 * 768 * sizeof(float),
                   hipMemcpyDeviceToDevice, stream);
}

// Round 5
// 1433.009 us; speedup vs baseline: 1.3787x; 1.1350x over previous
//
#include <hip/hip_runtime.h>

// ---------------------------------------------------------------------------
// Talking-heads transformer, 4 layers, f32 in/out (bf16 MFMA inside), gfx950.
// B=8 N=512 DIM=768 H=12 DH=64 MLP=3072 DEPTH=4 LS=0.1 EPS=1e-5
// ws layout (67.6 MB):
//   xf  f32  [4096,768]   @ 0          residual accumulator
//   h   bf16 [4096,768]   @ 12582912   LN out; also partial plane P0
//   qkv bf16 [4096,2304]  @ 18874368   q-slot doubles as attention-o and P1(W2)
//   S   bf16 [48,512,512] @ 37748736   attn scores chunk; MLP mid; P1(Wo)
//   Wt  bf16 [<=2359296]  @ 62914560   transposed bf16 weight [N,K]
// ---------------------------------------------------------------------------

#define LSCALE 0.1f

typedef __bf16 bf16;
typedef __bf16 bf16x8 __attribute__((ext_vector_type(8)));
typedef unsigned short ushort4v __attribute__((ext_vector_type(4)));
typedef float  f32x4  __attribute__((ext_vector_type(4)));

// async global->LDS, 16B/lane; LDS dest = wave-uniform base + lane*16B.
__device__ __forceinline__ void g2l16(const void* g, void* l) {
    __builtin_amdgcn_global_load_lds(
        (const __attribute__((address_space(1))) void*)g,
        (__attribute__((address_space(3))) void*)l, 16, 0, 0);
}

// ---------------------------------------------------------------------------
// Epilogue. EPI 0: C_bf16 = acc*scale
//           EPI 1: C_bf16 = gelu_tanh(acc + bias[col])
//           EPI 4: C_bf16 = acc              (split-K partial plane)
// C layout of mfma_f32_16x16x32_bf16: col = lane&15, row = (lane>>4)*4 + reg.
// ---------------------------------------------------------------------------
template<int EPI>
__device__ __forceinline__ void epilogue(
    f32x4 (&acc)[4][4], void* Cv, int ldc, long cb,
    int m0, int n0, int wr, int wc, int lr, int lq,
    int N, const float* bias, float scale)
{
#pragma unroll
    for (int ni = 0; ni < 4; ni++) {
        const int gc = n0 + wc + ni * 16 + lr;
        if (gc >= N) continue;
        float bv = 0.f;
        if (EPI == 1) bv = bias[gc];
#pragma unroll
        for (int mi = 0; mi < 4; mi++) {
#pragma unroll
            for (int r = 0; r < 4; r++) {
                const int gr = m0 + wr + mi * 16 + lq * 4 + r;  // M%128==0
                const long idx = cb + (long)gr * ldc + gc;
                if (EPI == 0) {
                    ((bf16*)Cv)[idx] = (bf16)(acc[mi][ni][r] * scale);
                } else if (EPI == 1) {
                    float xx = acc[mi][ni][r] + bv;
                    float u  = 0.7978845608f * (xx + 0.044715f * xx * xx * xx);
                    float th = 1.f - 2.f / (__expf(2.f * u) + 1.f);
                    ((bf16*)Cv)[idx] = (bf16)(0.5f * xx * (1.f + th));
                } else {
                    ((bf16*)Cv)[idx] = (bf16)acc[mi][ni][r];
                }
            }
        }
    }
}

// ---------------------------------------------------------------------------
// GEMM (Bt form): C[M,N] = A[M,K] @ Bt[N,K]^T   (A,Bt bf16, g2l16 staging)
// Block mapping: m-tile = blockIdx.x (grid.x = M/128, multiple of 8 -> blocks
// sharing an A-row land on one XCD for L2 reuse), n-tile = blockIdx.y.
// batched via z: z1=z/zmod, z2=z%zmod. split-K: zmod=2, saz2/sbz2 = k-offset,
// scz2 = partial-plane offset, K = per-slice k length.
// ---------------------------------------------------------------------------
template<int EPI>
__global__ __launch_bounds__(256, 2)
void gemm_bt(const bf16* __restrict__ A, int lda, long saz1, long saz2,
             const bf16* __restrict__ Bt, int ldb, long sbz1, long sbz2,
             void* __restrict__ Cv, int ldc, long scz1, long scz2,
             int M, int N, int K, int zmod,
             const float* __restrict__ bias, float scale)
{
    __shared__ __align__(16) bf16 As[128 * 32];
    __shared__ __align__(16) bf16 Bs[128 * 32];

    const int z  = blockIdx.z;
    const int z1 = z / zmod, z2 = z - z1 * zmod;
    const bf16* Ab = A  + saz1 * (long)z1 + saz2 * (long)z2;
    const bf16* Bb = Bt + sbz1 * (long)z1 + sbz2 * (long)z2;

    const int m0 = blockIdx.x * 128, n0 = blockIdx.y * 128;
    const int tid = threadIdx.x, w = tid >> 6, l = tid & 63;
    const int wr = (w >> 1) * 64, wc = (w & 1) * 64;
    const int lr = l & 15, lq = l >> 4;
    const int srow = l >> 2, scol8 = (l & 3) * 8;

    f32x4 acc[4][4];
#pragma unroll
    for (int i = 0; i < 4; i++)
#pragma unroll
        for (int j = 0; j < 4; j++)
#pragma unroll
            for (int r = 0; r < 4; r++) acc[i][j][r] = 0.f;

    bf16* Al = As + w * 1024;
    bf16* Bl = Bs + w * 1024;

    for (int k0 = 0; k0 < K; k0 += 32) {
        const bf16* Ag = Ab + (long)(m0 + w * 32) * lda + k0;
        const bf16* Bg = Bb + (long)(n0 + w * 32) * ldb + k0;
        g2l16(Ag + (long)srow * lda + scol8,        Al);
        g2l16(Ag + (long)(srow + 16) * lda + scol8, Al + 512);
        g2l16(Bg + (long)srow * ldb + scol8,        Bl);
        g2l16(Bg + (long)(srow + 16) * ldb + scol8, Bl + 512);
        __syncthreads();

        bf16x8 fa[4], fb[4];
#pragma unroll
        for (int i = 0; i < 4; i++)
            fa[i] = *(const bf16x8*)(As + (wr + i * 16 + lr) * 32 + lq * 8);
#pragma unroll
        for (int i = 0; i < 4; i++)
            fb[i] = *(const bf16x8*)(Bs + (wc + i * 16 + lr) * 32 + lq * 8);
#pragma unroll
        for (int mi = 0; mi < 4; mi++)
#pragma unroll
            for (int ni = 0; ni < 4; ni++)
                acc[mi][ni] = __builtin_amdgcn_mfma_f32_16x16x32_bf16(
                    fa[mi], fb[ni], acc[mi][ni], 0, 0, 0);
        __syncthreads();
    }

    epilogue<EPI>(acc, Cv, ldc, scz1 * (long)z1 + scz2 * (long)z2,
                  m0, n0, wr, wc, lr, lq, N, bias, scale);
}

// ---------------------------------------------------------------------------
// AV GEMM: o[b, i, g*64+d] = sum_j P[b,g,i,j] * v[b,j,g*64+d]
// One block: i-tile 128 x d 64, 4 waves stacked along i (32 rows each).
// A = S chunk plane (ld 512), B = v inside qkv (ld 2304), C = q-slot of qkv.
// grid (itile=4, z=48) where z = b*12+g (b chunk-local).
// ---------------------------------------------------------------------------
__global__ __launch_bounds__(256, 2)
void gemm_av(const bf16* __restrict__ S, const bf16* __restrict__ qkvc,
             bf16* __restrict__ oc)
{
    __shared__ __align__(16) bf16 As[128 * 32];
    __shared__ __align__(16) bf16 Bst[64 * 40];

    const int z = blockIdx.y, b = z / 12, g = z - b * 12;
    const bf16* Ab = S + (long)z * 262144;
    const bf16* Bb = qkvc + (long)b * 1179648 + 1536 + g * 64;  // v
    bf16* Cb = oc + (long)b * 1179648 + g * 64;                 // o in q-slot

    const int i0 = blockIdx.x * 128;
    const int tid = threadIdx.x, w = tid >> 6, l = tid & 63;
    const int lr = l & 15, lq = l >> 4;
    const int srow = l >> 2, scol8 = (l & 3) * 8;
    const int kp = tid >> 4, dq = tid & 15;   // j-pair, d-quad
    const int kcol = ((((kp >> 2) ^ ((dq >> 1) & 3)) << 3) | ((kp & 3) << 1));

    f32x4 acc[2][4];
#pragma unroll
    for (int i = 0; i < 2; i++)
#pragma unroll
        for (int j = 0; j < 4; j++)
#pragma unroll
            for (int r = 0; r < 4; r++) acc[i][j][r] = 0.f;

    bf16* Al = As + w * 1024;
    unsigned short* Bw = (unsigned short*)Bst;

    for (int k0 = 0; k0 < 512; k0 += 32) {
        const bf16* Ag = Ab + (long)(i0 + w * 32) * 512 + k0;
        g2l16(Ag + (long)srow * 512 + scol8,        Al);
        g2l16(Ag + (long)(srow + 16) * 512 + scol8, Al + 512);

        const bf16* Bg = Bb + (long)(k0 + 2 * kp) * 2304 + dq * 4;
        ushort4v u0 = *(const ushort4v*)(Bg);
        ushort4v u1 = *(const ushort4v*)(Bg + 2304);
#pragma unroll
        for (int r = 0; r < 4; r++) {
            unsigned p = (unsigned)u0[r] | ((unsigned)u1[r] << 16);
            *(unsigned*)(Bw + (dq * 4 + r) * 40 + kcol) = p;
        }
        __syncthreads();

        bf16x8 fa[2], fb[4];
#pragma unroll
        for (int i = 0; i < 2; i++)
            fa[i] = *(const bf16x8*)(As + (w * 32 + i * 16 + lr) * 32 + lq * 8);
#pragma unroll
        for (int i = 0; i < 4; i++) {
            const int d = i * 16 + lr;
            fb[i] = *(const bf16x8*)(Bst + d * 40 + ((lq ^ ((d >> 3) & 3)) << 3));
        }
#pragma unroll
        for (int mi = 0; mi < 2; mi++)
#pragma unroll
            for (int ni = 0; ni < 4; ni++)
                acc[mi][ni] = __builtin_amdgcn_mfma_f32_16x16x32_bf16(
                    fa[mi], fb[ni], acc[mi][ni], 0, 0, 0);
        __syncthreads();
    }

#pragma unroll
    for (int ni = 0; ni < 4; ni++) {
        const int gc = ni * 16 + lr;
#pragma unroll
        for (int mi = 0; mi < 2; mi++)
#pragma unroll
            for (int r = 0; r < 4; r++) {
                const int gr = i0 + w * 32 + mi * 16 + lq * 4 + r;
                Cb[(long)gr * 2304 + gc] = (bf16)acc[mi][ni][r];
            }
    }
}

// ---------------------------------------------------------------------------
// transpose+convert: in f32 [K,N] -> out bf16 [N,K].  32x32 tiles.
// ---------------------------------------------------------------------------
__global__ __launch_bounds__(256)
void tconv_k(const float* __restrict__ in, bf16* __restrict__ out,
             int K, int N)
{
    __shared__ float t[32][33];
    const int n0 = blockIdx.x * 32, k0 = blockIdx.y * 32;
    const int x = threadIdx.x, y = threadIdx.y;
#pragma unroll
    for (int yy = 0; yy < 4; yy++)
        t[y + yy * 8][x] = in[(long)(k0 + y + yy * 8) * N + n0 + x];
    __syncthreads();
#pragma unroll
    for (int yy = 0; yy < 4; yy++)
        out[(long)(n0 + y + yy * 8) * K + k0 + x] = (bf16)t[x][y + yy * 8];
}

// ---------------------------------------------------------------------------
// Fused residual-reduce + LayerNorm:
//   if P0: x = xf + LS*(P0 + P1 + bias); xf = x   (split-K partials, bf16)
//   out = (x-mu)*rsqrt(var+eps)*gamma
// one block per row of 768. Safe when out aliases P0 (row-local, read-first).
// ---------------------------------------------------------------------------
__global__ __launch_bounds__(256)
void lnres_k(float* __restrict__ xf, const bf16* __restrict__ P0,
             const bf16* __restrict__ P1, const float* __restrict__ bias,
             const float* __restrict__ gam, bf16* __restrict__ out)
{
    const int row = blockIdx.x, t = threadIdx.x;
    float* xr = xf + (long)row * 768;
    float v[3];
#pragma unroll
    for (int i = 0; i < 3; i++) {
        const int c = t + i * 256;
        float xv = xr[c];
        if (P0) {
            xv += LSCALE * ((float)P0[(long)row * 768 + c] +
                            (float)P1[(long)row * 768 + c] + bias[c]);
            xr[c] = xv;
        }
        v[i] = xv;
    }
    float s  = v[0] + v[1] + v[2];
    float ss = v[0] * v[0] + v[1] * v[1] + v[2] * v[2];
#pragma unroll
    for (int off = 32; off; off >>= 1) {
        s  += __shfl_xor(s, off);
        ss += __shfl_xor(ss, off);
    }
    __shared__ float ps[4], pss[4];
    const int wv = t >> 6, l = t & 63;
    if (l == 0) { ps[wv] = s; pss[wv] = ss; }
    __syncthreads();
    s  = ps[0] + ps[1] + ps[2] + ps[3];
    ss = pss[0] + pss[1] + pss[2] + pss[3];
    const float mu = s * (1.f / 768.f);
    const float rs = rsqrtf(ss * (1.f / 768.f) - mu * mu + 1e-5f);
    bf16* orow = out + (long)row * 768;
#pragma unroll
    for (int i = 0; i < 3; i++) {
        const int c = t + i * 256;
        orow[c] = (bf16)((v[i] - mu) * rs * gam[c]);
    }
}

// final: d_out = xf + LS*(P0 + P1 + bias)   (f32 out)
__global__ __launch_bounds__(256)
void outres_k(const float* __restrict__ xf, const bf16* __restrict__ P0,
              const bf16* __restrict__ P1, const float* __restrict__ bias,
              float* __restrict__ out)
{
    const long i = (long)blockIdx.x * 256 + threadIdx.x;
    const int c = (int)(i % 768);
    out[i] = xf[i] + LSCALE * ((float)P0[i] + (float)P1[i] + bias[c]);
}

// ---------------------------------------------------------------------------
// talking-heads mix (pre) -> softmax -> mix (post), in place on S chunk
// [4,12,512,512]. one block per (b-in-chunk, i). mp/mq f32 [12,12].
// ---------------------------------------------------------------------------
__global__ __launch_bounds__(256)
void mixsm_k(bf16* __restrict__ S, const float* __restrict__ mp,
             const float* __restrict__ mq)
{
    __shared__ float raw[12][512];
    __shared__ float buf[12][512];
    __shared__ float mpl[12][12], mql[12][12];
    const int b = blockIdx.y, i = blockIdx.x, t = threadIdx.x;
    bf16* Sb = S + ((long)b * 12 * 512 + i) * 512;

#pragma unroll
    for (int h2 = 0; h2 < 12; h2++)
        for (int j = t; j < 512; j += 256)
            raw[h2][j] = (float)Sb[(long)h2 * 262144 + j];
    if (t < 144) {
        mpl[t / 12][t % 12] = mp[t];
        mql[t / 12][t % 12] = mq[t];
    }
    __syncthreads();

    for (int g = 0; g < 12; g++)
        for (int j = t; j < 512; j += 256) {
            float a = 0.f;
#pragma unroll
            for (int h2 = 0; h2 < 12; h2++) a += raw[h2][j] * mpl[h2][g];
            buf[g][j] = a;
        }
    __syncthreads();

    const int wv = t >> 6, l = t & 63;
    for (int g = wv; g < 12; g += 4) {
        float mx = -3.0e38f;
        for (int j = l; j < 512; j += 64) mx = fmaxf(mx, buf[g][j]);
#pragma unroll
        for (int off = 32; off; off >>= 1) mx = fmaxf(mx, __shfl_xor(mx, off));
        float sm = 0.f;
        for (int j = l; j < 512; j += 64) {
            float e = __expf(buf[g][j] - mx);
            buf[g][j] = e; sm += e;
        }
#pragma unroll
        for (int off = 32; off; off >>= 1) sm += __shfl_xor(sm, off);
        const float inv = 1.f / sm;
        for (int j = l; j < 512; j += 64) buf[g][j] *= inv;
    }
    __syncthreads();

    for (int g = 0; g < 12; g++)
        for (int j = t; j < 512; j += 256) {
            float a = 0.f;
#pragma unroll
            for (int h2 = 0; h2 < 12; h2++) a += buf[h2][j] * mql[h2][g];
            Sb[(long)g * 262144 + j] = (bf16)a;
        }
}

// ---------------------------------------------------------------------------
extern "C" void kernel_launch(void* const* d_in, const int* in_sizes, int n_in,
                              void* d_out, int out_size, void* d_ws, size_t ws_size,
                              hipStream_t stream)
{
    (void)in_sizes; (void)n_in; (void)out_size; (void)ws_size;
    const float* x   = (const float*)d_in[0];
    const float* ln1 = (const float*)d_in[1];
    const float* Wq  = (const float*)d_in[2];
    const float* Wkv = (const float*)d_in[3];
    const float* mp  = (const float*)d_in[4];
    const float* mq  = (const float*)d_in[5];
    const float* Wo  = (const float*)d_in[6];
    const float* bo  = (const float*)d_in[7];
    const float* ln2 = (const float*)d_in[8];
    const float* W1  = (const float*)d_in[9];
    const float* b1  = (const float*)d_in[10];
    const float* W2  = (const float*)d_in[11];
    const float* b2  = (const float*)d_in[12];

    char* ws = (char*)d_ws;
    float* xf  = (float*)(ws);               // [4096,768] f32
    bf16* h    = (bf16*)(ws + 12582912);     // [4096,768]; partial plane P0
    bf16* qkv  = (bf16*)(ws + 18874368);     // [4096,2304]; o in q-slot; P1(W2)
    bf16* S    = (bf16*)(ws + 37748736);     // [48,512,512]; MLP mid; P1(Wo)
    bf16* Wt   = (bf16*)(ws + 62914560);     // transposed bf16 weight
    bf16* mid  = S;
    bf16* P0   = h;
    bf16* P1w2 = qkv;
    bf16* P1wo = S;
    const long P1W2_OFF = 3145728;           // (qkv - h) in elements
    const long P1WO_OFF = 12582912;          // (S - h) in elements

    const dim3 tb(32, 8);

    hipMemcpyAsync(xf, x, 4096 * 768 * sizeof(float),
                   hipMemcpyDeviceToDevice, stream);

    for (int L = 0; L < 4; L++) {
        tconv_k<<<dim3(24, 24), tb, 0, stream>>>(Wq + (long)L * 589824, Wt, 768, 768);
        tconv_k<<<dim3(48, 24), tb, 0, stream>>>(Wkv + (long)L * 1179648, Wt + 589824, 768, 1536);

        // x += LS*(prev-W2 partials + b2_{L-1}) [L>0]; h = LN(x)*ln1
        if (L == 0)
            lnres_k<<<4096, 256, 0, stream>>>(xf, nullptr, nullptr, nullptr,
                                              ln1 + L * 768, h);
        else
            lnres_k<<<4096, 256, 0, stream>>>(xf, P0, P1w2, b2 + (L - 1) * 768,
                                              ln1 + L * 768, h);

        // qkv = h @ [Wq | Wkv]
        gemm_bt<0><<<dim3(32, 18, 1), 256, 0, stream>>>(
            h, 768, 0, 0, Wt, 768, 0, 0,
            qkv, 2304, 0, 0, 4096, 2304, 768, 1, nullptr, 1.f);

        // attention in 2 chunks of 4 batches
        for (int c = 0; c < 2; c++) {
            const long qb = (long)c * 4718592;
            gemm_bt<0><<<dim3(4, 4, 48), 256, 0, stream>>>(
                qkv + qb,       2304, 1179648, 64,
                qkv + 768 + qb, 2304, 1179648, 64,
                S,               512, 3145728, 262144,
                512, 512, 64, 12, nullptr, 0.125f);

            mixsm_k<<<dim3(512, 4), 256, 0, stream>>>(S, mp + L * 144, mq + L * 144);

            // o (q-slot of this chunk) = attn @ v
            gemm_av<<<dim3(4, 48), 256, 0, stream>>>(S, qkv + qb, qkv + qb);
        }

        // Wo partials: P0/P1wo = o @ Wo (split-K=2)
        tconv_k<<<dim3(24, 24), tb, 0, stream>>>(Wo + (long)L * 589824, Wt, 768, 768);
        gemm_bt<4><<<dim3(32, 6, 2), 256, 0, stream>>>(
            qkv, 2304, 0, 384, Wt, 768, 0, 384,
            P0, 768, 0, P1WO_OFF, 4096, 768, 384, 2, nullptr, 1.f);

        // x += LS*(P0+P1+bo); h = LN(x)*ln2
        lnres_k<<<4096, 256, 0, stream>>>(xf, P0, P1wo, bo + L * 768,
                                          ln2 + L * 768, h);

        // mid = gelu(h @ W1 + b1)
        tconv_k<<<dim3(96, 24), tb, 0, stream>>>(W1 + (long)L * 2359296, Wt, 768, 3072);
        gemm_bt<1><<<dim3(32, 24, 1), 256, 0, stream>>>(
            h, 768, 0, 0, Wt, 768, 0, 0,
            mid, 3072, 0, 0, 4096, 3072, 768, 1, b1 + L * 3072, 1.f);

        // W2 partials: P0/P1w2 = mid @ W2 (split-K=2)
        tconv_k<<<dim3(24, 96), tb, 0, stream>>>(W2 + (long)L * 2359296, Wt, 3072, 768);
        gemm_bt<4><<<dim3(32, 6, 2), 256, 0, stream>>>(
            mid, 3072, 0, 1536, Wt, 3072, 0, 1536,
            P0, 768, 0, P1W2_OFF, 4096, 768, 1536, 2, nullptr, 1.f);
    }

    // d_out = xf + LS*(P0+P1+b2_3)
    outres_k<<<12288, 256, 0, stream>>>(xf, P0, P1w2, b2 + 3 * 768, (float*)d_out);
}

// Round 6
// 1098.207 us; speedup vs baseline: 1.7990x; 1.3049x over previous
//
#include <hip/hip_runtime.h>

// ---------------------------------------------------------------------------
// Talking-heads transformer, 4 layers, f32 in/out (bf16 MFMA inside), gfx950.
// B=8 N=512 DIM=768 H=12 DH=64 MLP=3072 DEPTH=4 LS=0.1 EPS=1e-5
// ws layout (67.6 MB):
//   xf  f32  [4096,768]   @ 0          residual accumulator
//   h   bf16 [4096,768]   @ 12582912   LN out; also partial plane P0
//   qkv bf16 [4096,2304]  @ 18874368   q-slot doubles as attention-o and P1(W2)
//   S   bf16 [48,512,512] @ 37748736   attn scores chunk; MLP mid; P1(Wo)
//   Wt  bf16 [<=2359296]  @ 62914560   transposed bf16 weight [N,K]
// ---------------------------------------------------------------------------

#define LSCALE 0.1f

typedef __bf16 bf16;
typedef __bf16 bf16x8 __attribute__((ext_vector_type(8)));
typedef unsigned short ushort4v __attribute__((ext_vector_type(4)));
typedef float  f32x4  __attribute__((ext_vector_type(4)));

// async global->LDS, 16B/lane; LDS dest = wave-uniform base + lane*16B.
__device__ __forceinline__ void g2l16(const void* g, void* l) {
    __builtin_amdgcn_global_load_lds(
        (const __attribute__((address_space(1))) void*)g,
        (__attribute__((address_space(3))) void*)l, 16, 0, 0);
}

// ---------------------------------------------------------------------------
// Epilogue. EPI 0: C_bf16 = acc*scale
//           EPI 1: C_bf16 = gelu_tanh(acc + bias[col])
//           EPI 4: C_bf16 = acc              (split-K partial plane)
// C layout of mfma_f32_16x16x32_bf16: col = lane&15, row = (lane>>4)*4 + reg.
// ---------------------------------------------------------------------------
template<int EPI>
__device__ __forceinline__ void epilogue(
    f32x4 (&acc)[4][4], void* Cv, int ldc, long cb,
    int m0, int n0, int wr, int wc, int lr, int lq,
    int N, const float* bias, float scale)
{
#pragma unroll
    for (int ni = 0; ni < 4; ni++) {
        const int gc = n0 + wc + ni * 16 + lr;
        if (gc >= N) continue;
        float bv = 0.f;
        if (EPI == 1) bv = bias[gc];
#pragma unroll
        for (int mi = 0; mi < 4; mi++) {
#pragma unroll
            for (int r = 0; r < 4; r++) {
                const int gr = m0 + wr + mi * 16 + lq * 4 + r;  // M%128==0
                const long idx = cb + (long)gr * ldc + gc;
                if (EPI == 0) {
                    ((bf16*)Cv)[idx] = (bf16)(acc[mi][ni][r] * scale);
                } else if (EPI == 1) {
                    float xx = acc[mi][ni][r] + bv;
                    float u  = 0.7978845608f * (xx + 0.044715f * xx * xx * xx);
                    float th = 1.f - 2.f / (__expf(2.f * u) + 1.f);
                    ((bf16*)Cv)[idx] = (bf16)(0.5f * xx * (1.f + th));
                } else {
                    ((bf16*)Cv)[idx] = (bf16)acc[mi][ni][r];
                }
            }
        }
    }
}

// ---------------------------------------------------------------------------
// GEMM (Bt form): C[M,N] = A[M,K] @ Bt[N,K]^T   (A,Bt bf16, g2l16 staging)
// Block mapping: m-tile = blockIdx.x (grid.x = M/128, multiple of 8 -> blocks
// sharing an A-row land on one XCD for L2 reuse), n-tile = blockIdx.y.
// batched via z: z1=z/zmod, z2=z%zmod. split-K: zmod=2, saz2/sbz2 = k-offset,
// scz2 = partial-plane offset, K = per-slice k length.
// ---------------------------------------------------------------------------
template<int EPI>
__global__ __launch_bounds__(256, 2)
void gemm_bt(const bf16* __restrict__ A, int lda, long saz1, long saz2,
             const bf16* __restrict__ Bt, int ldb, long sbz1, long sbz2,
             void* __restrict__ Cv, int ldc, long scz1, long scz2,
             int M, int N, int K, int zmod,
             const float* __restrict__ bias, float scale)
{
    __shared__ __align__(16) bf16 As[128 * 32];
    __shared__ __align__(16) bf16 Bs[128 * 32];

    const int z  = blockIdx.z;
    const int z1 = z / zmod, z2 = z - z1 * zmod;
    const bf16* Ab = A  + saz1 * (long)z1 + saz2 * (long)z2;
    const bf16* Bb = Bt + sbz1 * (long)z1 + sbz2 * (long)z2;

    const int m0 = blockIdx.x * 128, n0 = blockIdx.y * 128;
    const int tid = threadIdx.x, w = tid >> 6, l = tid & 63;
    const int wr = (w >> 1) * 64, wc = (w & 1) * 64;
    const int lr = l & 15, lq = l >> 4;
    const int srow = l >> 2, scol8 = (l & 3) * 8;

    f32x4 acc[4][4];
#pragma unroll
    for (int i = 0; i < 4; i++)
#pragma unroll
        for (int j = 0; j < 4; j++)
#pragma unroll
            for (int r = 0; r < 4; r++) acc[i][j][r] = 0.f;

    bf16* Al = As + w * 1024;
    bf16* Bl = Bs + w * 1024;

    for (int k0 = 0; k0 < K; k0 += 32) {
        const bf16* Ag = Ab + (long)(m0 + w * 32) * lda + k0;
        const bf16* Bg = Bb + (long)(n0 + w * 32) * ldb + k0;
        g2l16(Ag + (long)srow * lda + scol8,        Al);
        g2l16(Ag + (long)(srow + 16) * lda + scol8, Al + 512);
        g2l16(Bg + (long)srow * ldb + scol8,        Bl);
        g2l16(Bg + (long)(srow + 16) * ldb + scol8, Bl + 512);
        __syncthreads();

        bf16x8 fa[4], fb[4];
#pragma unroll
        for (int i = 0; i < 4; i++)
            fa[i] = *(const bf16x8*)(As + (wr + i * 16 + lr) * 32 + lq * 8);
#pragma unroll
        for (int i = 0; i < 4; i++)
            fb[i] = *(const bf16x8*)(Bs + (wc + i * 16 + lr) * 32 + lq * 8);
#pragma unroll
        for (int mi = 0; mi < 4; mi++)
#pragma unroll
            for (int ni = 0; ni < 4; ni++)
                acc[mi][ni] = __builtin_amdgcn_mfma_f32_16x16x32_bf16(
                    fa[mi], fb[ni], acc[mi][ni], 0, 0, 0);
        __syncthreads();
    }

    epilogue<EPI>(acc, Cv, ldc, scz1 * (long)z1 + scz2 * (long)z2,
                  m0, n0, wr, wc, lr, lq, N, bias, scale);
}

// ---------------------------------------------------------------------------
// AV GEMM: o[b, i, g*64+d] = sum_j P[b,g,i,j] * v[b,j,g*64+d]
// One block: i-tile 128 x d 64, 4 waves stacked along i (32 rows each).
// ---------------------------------------------------------------------------
__global__ __launch_bounds__(256, 2)
void gemm_av(const bf16* __restrict__ S, const bf16* __restrict__ qkvc,
             bf16* __restrict__ oc)
{
    __shared__ __align__(16) bf16 As[128 * 32];
    __shared__ __align__(16) bf16 Bst[64 * 40];

    const int z = blockIdx.y, b = z / 12, g = z - b * 12;
    const bf16* Ab = S + (long)z * 262144;
    const bf16* Bb = qkvc + (long)b * 1179648 + 1536 + g * 64;  // v
    bf16* Cb = oc + (long)b * 1179648 + g * 64;                 // o in q-slot

    const int i0 = blockIdx.x * 128;
    const int tid = threadIdx.x, w = tid >> 6, l = tid & 63;
    const int lr = l & 15, lq = l >> 4;
    const int srow = l >> 2, scol8 = (l & 3) * 8;
    const int kp = tid >> 4, dq = tid & 15;   // j-pair, d-quad
    const int kcol = ((((kp >> 2) ^ ((dq >> 1) & 3)) << 3) | ((kp & 3) << 1));

    f32x4 acc[2][4];
#pragma unroll
    for (int i = 0; i < 2; i++)
#pragma unroll
        for (int j = 0; j < 4; j++)
#pragma unroll
            for (int r = 0; r < 4; r++) acc[i][j][r] = 0.f;

    bf16* Al = As + w * 1024;
    unsigned short* Bw = (unsigned short*)Bst;

    for (int k0 = 0; k0 < 512; k0 += 32) {
        const bf16* Ag = Ab + (long)(i0 + w * 32) * 512 + k0;
        g2l16(Ag + (long)srow * 512 + scol8,        Al);
        g2l16(Ag + (long)(srow + 16) * 512 + scol8, Al + 512);

        const bf16* Bg = Bb + (long)(k0 + 2 * kp) * 2304 + dq * 4;
        ushort4v u0 = *(const ushort4v*)(Bg);
        ushort4v u1 = *(const ushort4v*)(Bg + 2304);
#pragma unroll
        for (int r = 0; r < 4; r++) {
            unsigned p = (unsigned)u0[r] | ((unsigned)u1[r] << 16);
            *(unsigned*)(Bw + (dq * 4 + r) * 40 + kcol) = p;
        }
        __syncthreads();

        bf16x8 fa[2], fb[4];
#pragma unroll
        for (int i = 0; i < 2; i++)
            fa[i] = *(const bf16x8*)(As + (w * 32 + i * 16 + lr) * 32 + lq * 8);
#pragma unroll
        for (int i = 0; i < 4; i++) {
            const int d = i * 16 + lr;
            fb[i] = *(const bf16x8*)(Bst + d * 40 + ((lq ^ ((d >> 3) & 3)) << 3));
        }
#pragma unroll
        for (int mi = 0; mi < 2; mi++)
#pragma unroll
            for (int ni = 0; ni < 4; ni++)
                acc[mi][ni] = __builtin_amdgcn_mfma_f32_16x16x32_bf16(
                    fa[mi], fb[ni], acc[mi][ni], 0, 0, 0);
        __syncthreads();
    }

#pragma unroll
    for (int ni = 0; ni < 4; ni++) {
        const int gc = ni * 16 + lr;
#pragma unroll
        for (int mi = 0; mi < 2; mi++)
#pragma unroll
            for (int r = 0; r < 4; r++) {
                const int gr = i0 + w * 32 + mi * 16 + lq * 4 + r;
                Cb[(long)gr * 2304 + gc] = (bf16)acc[mi][ni][r];
            }
    }
}

// ---------------------------------------------------------------------------
// transpose+convert: in f32 [K,N] -> out bf16 [N,K].  32x32 tiles.
// ---------------------------------------------------------------------------
__global__ __launch_bounds__(256)
void tconv_k(const float* __restrict__ in, bf16* __restrict__ out,
             int K, int N)
{
    __shared__ float t[32][33];
    const int n0 = blockIdx.x * 32, k0 = blockIdx.y * 32;
    const int x = threadIdx.x, y = threadIdx.y;
#pragma unroll
    for (int yy = 0; yy < 4; yy++)
        t[y + yy * 8][x] = in[(long)(k0 + y + yy * 8) * N + n0 + x];
    __syncthreads();
#pragma unroll
    for (int yy = 0; yy < 4; yy++)
        out[(long)(n0 + y + yy * 8) * K + k0 + x] = (bf16)t[x][y + yy * 8];
}

// ---------------------------------------------------------------------------
// Fused residual-reduce + LayerNorm.
// ---------------------------------------------------------------------------
__global__ __launch_bounds__(256)
void lnres_k(float* __restrict__ xf, const bf16* __restrict__ P0,
             const bf16* __restrict__ P1, const float* __restrict__ bias,
             const float* __restrict__ gam, bf16* __restrict__ out)
{
    const int row = blockIdx.x, t = threadIdx.x;
    float* xr = xf + (long)row * 768;
    float v[3];
#pragma unroll
    for (int i = 0; i < 3; i++) {
        const int c = t + i * 256;
        float xv = xr[c];
        if (P0) {
            xv += LSCALE * ((float)P0[(long)row * 768 + c] +
                            (float)P1[(long)row * 768 + c] + bias[c]);
            xr[c] = xv;
        }
        v[i] = xv;
    }
    float s  = v[0] + v[1] + v[2];
    float ss = v[0] * v[0] + v[1] * v[1] + v[2] * v[2];
#pragma unroll
    for (int off = 32; off; off >>= 1) {
        s  += __shfl_xor(s, off);
        ss += __shfl_xor(ss, off);
    }
    __shared__ float ps[4], pss[4];
    const int wv = t >> 6, l = t & 63;
    if (l == 0) { ps[wv] = s; pss[wv] = ss; }
    __syncthreads();
    s  = ps[0] + ps[1] + ps[2] + ps[3];
    ss = pss[0] + pss[1] + pss[2] + pss[3];
    const float mu = s * (1.f / 768.f);
    const float rs = rsqrtf(ss * (1.f / 768.f) - mu * mu + 1e-5f);
    bf16* orow = out + (long)row * 768;
#pragma unroll
    for (int i = 0; i < 3; i++) {
        const int c = t + i * 256;
        orow[c] = (bf16)((v[i] - mu) * rs * gam[c]);
    }
}

// final: d_out = xf + LS*(P0 + P1 + bias)   (f32 out)
__global__ __launch_bounds__(256)
void outres_k(const float* __restrict__ xf, const bf16* __restrict__ P0,
              const bf16* __restrict__ P1, const float* __restrict__ bias,
              float* __restrict__ out)
{
    const long i = (long)blockIdx.x * 256 + threadIdx.x;
    const int c = (int)(i % 768);
    out[i] = xf[i] + LSCALE * ((float)P0[i] + (float)P1[i] + bias[c]);
}

// ---------------------------------------------------------------------------
// talking-heads mix (pre) -> softmax -> mix (post), in place on S chunk
// [4,12,512,512]. one block per (b-in-chunk, i); thread owns j-pair (2t,2t+1).
// Register-blocked: h-values live in VGPRs; mix coeffs read via uniform
// global index -> s_load/SGPR operands (no LDS for coefficients).
// LDS: buf[12][512] f32 = 24 KB -> 6 blocks/CU.
// ---------------------------------------------------------------------------
__global__ __launch_bounds__(256)
void mixsm_k(bf16* __restrict__ S, const float* __restrict__ mp,
             const float* __restrict__ mq)
{
    __shared__ float buf[12][512];
    __shared__ float rds[12];
    const int b = blockIdx.y, i = blockIdx.x, t = threadIdx.x;
    bf16* Sb = S + ((long)b * 12 * 512 + i) * 512;

    // phase A: pre-mix in registers, one j-pair per thread
    float s0[12], s1[12];
#pragma unroll
    for (int h = 0; h < 12; h++) {
        union { unsigned u; bf16 v[2]; } p;
        p.u = *(const unsigned*)(Sb + (long)h * 262144 + 2 * t);
        s0[h] = (float)p.v[0];
        s1[h] = (float)p.v[1];
    }
#pragma unroll
    for (int g = 0; g < 12; g++) {
        float a0 = 0.f, a1 = 0.f;
#pragma unroll
        for (int h = 0; h < 12; h++) {
            const float m = mp[h * 12 + g];     // uniform -> SGPR
            a0 += s0[h] * m;
            a1 += s1[h] * m;
        }
        *(float2*)(&buf[g][2 * t]) = make_float2(a0, a1);
    }
    __syncthreads();

    // phase B: row softmax stats; overwrite buf with exp(v - max)
    const int wv = t >> 6, l = t & 63;
    for (int g = wv; g < 12; g += 4) {
        float mx = -3.0e38f;
#pragma unroll
        for (int k = 0; k < 8; k++) mx = fmaxf(mx, buf[g][l + 64 * k]);
#pragma unroll
        for (int off = 32; off; off >>= 1) mx = fmaxf(mx, __shfl_xor(mx, off));
        float sm = 0.f;
#pragma unroll
        for (int k = 0; k < 8; k++) {
            const float e = __expf(buf[g][l + 64 * k] - mx);
            buf[g][l + 64 * k] = e;
            sm += e;
        }
#pragma unroll
        for (int off = 32; off; off >>= 1) sm += __shfl_xor(sm, off);
        if (l == 0) rds[g] = 1.f / sm;
    }
    __syncthreads();

    // phase C: post-mix from registers, write bf16 pairs
    float e0[12], e1[12];
#pragma unroll
    for (int h = 0; h < 12; h++) {
        const float2 ee = *(const float2*)(&buf[h][2 * t]);
        const float rd = rds[h];
        e0[h] = ee.x * rd;
        e1[h] = ee.y * rd;
    }
#pragma unroll
    for (int g = 0; g < 12; g++) {
        float a0 = 0.f, a1 = 0.f;
#pragma unroll
        for (int h = 0; h < 12; h++) {
            const float m = mq[h * 12 + g];     // uniform -> SGPR
            a0 += e0[h] * m;
            a1 += e1[h] * m;
        }
        union { unsigned u; bf16 v[2]; } p;
        p.v[0] = (bf16)a0;
        p.v[1] = (bf16)a1;
        *(unsigned*)(Sb + (long)g * 262144 + 2 * t) = p.u;
    }
}

// ---------------------------------------------------------------------------
extern "C" void kernel_launch(void* const* d_in, const int* in_sizes, int n_in,
                              void* d_out, int out_size, void* d_ws, size_t ws_size,
                              hipStream_t stream)
{
    (void)in_sizes; (void)n_in; (void)out_size; (void)ws_size;
    const float* x   = (const float*)d_in[0];
    const float* ln1 = (const float*)d_in[1];
    const float* Wq  = (const float*)d_in[2];
    const float* Wkv = (const float*)d_in[3];
    const float* mp  = (const float*)d_in[4];
    const float* mq  = (const float*)d_in[5];
    const float* Wo  = (const float*)d_in[6];
    const float* bo  = (const float*)d_in[7];
    const float* ln2 = (const float*)d_in[8];
    const float* W1  = (const float*)d_in[9];
    const float* b1  = (const float*)d_in[10];
    const float* W2  = (const float*)d_in[11];
    const float* b2  = (const float*)d_in[12];

    char* ws = (char*)d_ws;
    float* xf  = (float*)(ws);               // [4096,768] f32
    bf16* h    = (bf16*)(ws + 12582912);     // [4096,768]; partial plane P0
    bf16* qkv  = (bf16*)(ws + 18874368);     // [4096,2304]; o in q-slot; P1(W2)
    bf16* S    = (bf16*)(ws + 37748736);     // [48,512,512]; MLP mid; P1(Wo)
    bf16* Wt   = (bf16*)(ws + 62914560);     // transposed bf16 weight
    bf16* mid  = S;
    bf16* P0   = h;
    bf16* P1w2 = qkv;
    bf16* P1wo = S;
    const long P1W2_OFF = 3145728;           // (qkv - h) in elements
    const long P1WO_OFF = 12582912;          // (S - h) in elements

    const dim3 tb(32, 8);

    hipMemcpyAsync(xf, x, 4096 * 768 * sizeof(float),
                   hipMemcpyDeviceToDevice, stream);

    for (int L = 0; L < 4; L++) {
        tconv_k<<<dim3(24, 24), tb, 0, stream>>>(Wq + (long)L * 589824, Wt, 768, 768);
        tconv_k<<<dim3(48, 24), tb, 0, stream>>>(Wkv + (long)L * 1179648, Wt + 589824, 768, 1536);

        // x += LS*(prev-W2 partials + b2_{L-1}) [L>0]; h = LN(x)*ln1
        if (L == 0)
            lnres_k<<<4096, 256, 0, stream>>>(xf, nullptr, nullptr, nullptr,
                                              ln1 + L * 768, h);
        else
            lnres_k<<<4096, 256, 0, stream>>>(xf, P0, P1w2, b2 + (L - 1) * 768,
                                              ln1 + L * 768, h);

        // qkv = h @ [Wq | Wkv]
        gemm_bt<0><<<dim3(32, 18, 1), 256, 0, stream>>>(
            h, 768, 0, 0, Wt, 768, 0, 0,
            qkv, 2304, 0, 0, 4096, 2304, 768, 1, nullptr, 1.f);

        // attention in 2 chunks of 4 batches
        for (int c = 0; c < 2; c++) {
            const long qb = (long)c * 4718592;
            gemm_bt<0><<<dim3(4, 4, 48), 256, 0, stream>>>(
                qkv + qb,       2304, 1179648, 64,
                qkv + 768 + qb, 2304, 1179648, 64,
                S,               512, 3145728, 262144,
                512, 512, 64, 12, nullptr, 0.125f);

            mixsm_k<<<dim3(512, 4), 256, 0, stream>>>(S, mp + L * 144, mq + L * 144);

            // o (q-slot of this chunk) = attn @ v
            gemm_av<<<dim3(4, 48), 256, 0, stream>>>(S, qkv + qb, qkv + qb);
        }

        // Wo partials: P0/P1wo = o @ Wo (split-K=2)
        tconv_k<<<dim3(24, 24), tb, 0, stream>>>(Wo + (long)L * 589824, Wt, 768, 768);
        gemm_bt<4><<<dim3(32, 6, 2), 256, 0, stream>>>(
            qkv, 2304, 0, 384, Wt, 768, 0, 384,
            P0, 768, 0, P1WO_OFF, 4096, 768, 384, 2, nullptr, 1.f);

        // x += LS*(P0+P1+bo); h = LN(x)*ln2
        lnres_k<<<4096, 256, 0, stream>>>(xf, P0, P1wo, bo + L * 768,
                                          ln2 + L * 768, h);

        // mid = gelu(h @ W1 + b1)
        tconv_k<<<dim3(96, 24), tb, 0, stream>>>(W1 + (long)L * 2359296, Wt, 768, 3072);
        gemm_bt<1><<<dim3(32, 24, 1), 256, 0, stream>>>(
            h, 768, 0, 0, Wt, 768, 0, 0,
            mid, 3072, 0, 0, 4096, 3072, 768, 1, b1 + L * 3072, 1.f);

        // W2 partials: P0/P1w2 = mid @ W2 (split-K=2)
        tconv_k<<<dim3(24, 96), tb, 0, stream>>>(W2 + (long)L * 2359296, Wt, 3072, 768);
        gemm_bt<4><<<dim3(32, 6, 2), 256, 0, stream>>>(
            mid, 3072, 0, 1536, Wt, 3072, 0, 1536,
            P0, 768, 0, P1W2_OFF, 4096, 768, 1536, 2, nullptr, 1.f);
    }

    // d_out = xf + LS*(P0+P1+b2_3)
    outres_k<<<12288, 256, 0, stream>>>(xf, P0, P1w2, b2 + 3 * 768, (float*)d_out);
}

// Round 7
// 1020.907 us; speedup vs baseline: 1.9352x; 1.0757x over previous
//
#include <hip/hip_runtime.h>

// ---------------------------------------------------------------------------
// Talking-heads transformer, 4 layers, f32 in/out (bf16 MFMA inside), gfx950.
// B=8 N=512 DIM=768 H=12 DH=64 MLP=3072 DEPTH=4 LS=0.1 EPS=1e-5
// ws layout (67.6 MB):
//   xf  f32  [4096,768]   @ 0          residual accumulator
//   h   bf16 [4096,768]   @ 12582912   LN out; also partial plane P0
//   qkv bf16 [4096,2304]  @ 18874368   q-slot doubles as attention-o and P1(W2)
//   S   bf16 [48,512,512] @ 37748736   attn scores chunk; MLP mid; P1(Wo)
//   Wt  bf16 [<=2359296]  @ 62914560   transposed bf16 weight [N,K]
// ---------------------------------------------------------------------------

#define LSCALE 0.1f

typedef __bf16 bf16;
typedef __bf16 bf16x8 __attribute__((ext_vector_type(8)));
typedef unsigned short ushort4v __attribute__((ext_vector_type(4)));
typedef float  f32x4  __attribute__((ext_vector_type(4)));

// async global->LDS, 16B/lane; LDS dest = wave-uniform base + lane*16B.
__device__ __forceinline__ void g2l16(const void* g, void* l) {
    __builtin_amdgcn_global_load_lds(
        (const __attribute__((address_space(1))) void*)g,
        (__attribute__((address_space(3))) void*)l, 16, 0, 0);
}

// ---------------------------------------------------------------------------
// GEMM (Bt form): C[M,N] = A[M,K] @ Bt[N,K]^T   (A,Bt bf16, g2l16 staging)
// BK=64 (two 32-k halves per barrier). N % 128 == 0, M % 128 == 0, K % 64 == 0.
// Epilogue: EPI 0 C=acc*scale | EPI 1 C=gelu(acc+bias) | EPI 4 C=acc (partial)
// C staged through LDS (128x136 bf16) for full-line coalesced 16B stores.
// split-K via z: z1=z/zmod, z2=z%zmod; saz2/sbz2 = k-offsets, scz2 = C offset.
// ---------------------------------------------------------------------------
template<int EPI>
__global__ __launch_bounds__(256, 2)
void gemm_bt(const bf16* __restrict__ A, int lda, long saz1, long saz2,
             const bf16* __restrict__ Bt, int ldb, long sbz1, long sbz2,
             void* __restrict__ Cv, int ldc, long scz1, long scz2,
             int M, int N, int K, int zmod,
             const float* __restrict__ bias, float scale)
{
    __shared__ __align__(16) char smem[35840];   // staging 32KB | bounce 34.8KB
    bf16* As = (bf16*)smem;                      // [2][128*32]
    bf16* Bs = (bf16*)(smem + 16384);            // [2][128*32]
    bf16* Cs = (bf16*)smem;                      // [128][136] (aliases staging)

    const int z  = blockIdx.z;
    const int z1 = z / zmod, z2 = z - z1 * zmod;
    const bf16* Ab = A  + saz1 * (long)z1 + saz2 * (long)z2;
    const bf16* Bb = Bt + sbz1 * (long)z1 + sbz2 * (long)z2;

    const int m0 = blockIdx.x * 128, n0 = blockIdx.y * 128;
    const int tid = threadIdx.x, w = tid >> 6, l = tid & 63;
    const int wr = (w >> 1) * 64, wc = (w & 1) * 64;
    const int lr = l & 15, lq = l >> 4;
    const int srow = l >> 2, scol8 = (l & 3) * 8;

    f32x4 acc[4][4];
#pragma unroll
    for (int i = 0; i < 4; i++)
#pragma unroll
        for (int j = 0; j < 4; j++)
#pragma unroll
            for (int r = 0; r < 4; r++) acc[i][j][r] = 0.f;

    for (int k0 = 0; k0 < K; k0 += 64) {
        const bf16* Ag = Ab + (long)(m0 + w * 32) * lda + k0;
        const bf16* Bg = Bb + (long)(n0 + w * 32) * ldb + k0;
        g2l16(Ag + (long)srow * lda + scol8,             As + w * 1024);
        g2l16(Ag + (long)(srow + 16) * lda + scol8,      As + w * 1024 + 512);
        g2l16(Ag + (long)srow * lda + 32 + scol8,        As + 4096 + w * 1024);
        g2l16(Ag + (long)(srow + 16) * lda + 32 + scol8, As + 4096 + w * 1024 + 512);
        g2l16(Bg + (long)srow * ldb + scol8,             Bs + w * 1024);
        g2l16(Bg + (long)(srow + 16) * ldb + scol8,      Bs + w * 1024 + 512);
        g2l16(Bg + (long)srow * ldb + 32 + scol8,        Bs + 4096 + w * 1024);
        g2l16(Bg + (long)(srow + 16) * ldb + 32 + scol8, Bs + 4096 + w * 1024 + 512);
        __syncthreads();

#pragma unroll
        for (int hh = 0; hh < 2; hh++) {
            bf16x8 fa[4], fb[4];
#pragma unroll
            for (int i = 0; i < 4; i++)
                fa[i] = *(const bf16x8*)(As + hh * 4096 + (wr + i * 16 + lr) * 32 + lq * 8);
#pragma unroll
            for (int i = 0; i < 4; i++)
                fb[i] = *(const bf16x8*)(Bs + hh * 4096 + (wc + i * 16 + lr) * 32 + lq * 8);
#pragma unroll
            for (int mi = 0; mi < 4; mi++)
#pragma unroll
                for (int ni = 0; ni < 4; ni++)
                    acc[mi][ni] = __builtin_amdgcn_mfma_f32_16x16x32_bf16(
                        fa[mi], fb[ni], acc[mi][ni], 0, 0, 0);
        }
        __syncthreads();
    }

    // ---- epilogue: transform, bounce through LDS, coalesced 16B stores ----
#pragma unroll
    for (int ni = 0; ni < 4; ni++) {
        const int col = wc + ni * 16 + lr;
        float bv = 0.f;
        if (EPI == 1) bv = bias[n0 + col];
#pragma unroll
        for (int mi = 0; mi < 4; mi++) {
#pragma unroll
            for (int r = 0; r < 4; r++) {
                const int row = wr + mi * 16 + lq * 4 + r;
                float v = acc[mi][ni][r];
                if (EPI == 0) {
                    v *= scale;
                } else if (EPI == 1) {
                    const float xx = v + bv;
                    const float u  = 0.7978845608f * (xx + 0.044715f * xx * xx * xx);
                    const float th = 1.f - 2.f / (__expf(2.f * u) + 1.f);
                    v = 0.5f * xx * (1.f + th);
                }
                Cs[row * 136 + col] = (bf16)v;
            }
        }
    }
    __syncthreads();

    const long cb = scz1 * (long)z1 + scz2 * (long)z2;
    const int rrow = tid >> 4, cg = tid & 15;
#pragma unroll
    for (int p = 0; p < 8; p++) {
        const int row = p * 16 + rrow;
        const bf16x8 v = *(const bf16x8*)(Cs + row * 136 + cg * 8);
        *(bf16x8*)((bf16*)Cv + cb + (long)(m0 + row) * ldc + n0 + cg * 8) = v;
    }
}

// ---------------------------------------------------------------------------
// AV GEMM: o[b, i, g*64+d] = sum_j P[b,g,i,j] * v[b,j,g*64+d]
// One block: i-tile 128 x d 64, 4 waves stacked along i (32 rows each).
// ---------------------------------------------------------------------------
__global__ __launch_bounds__(256, 2)
void gemm_av(const bf16* __restrict__ S, const bf16* __restrict__ qkvc,
             bf16* __restrict__ oc)
{
    __shared__ __align__(16) bf16 As[128 * 32];
    __shared__ __align__(16) bf16 Bst[64 * 40];

    const int z = blockIdx.y, b = z / 12, g = z - b * 12;
    const bf16* Ab = S + (long)z * 262144;
    const bf16* Bb = qkvc + (long)b * 1179648 + 1536 + g * 64;  // v
    bf16* Cb = oc + (long)b * 1179648 + g * 64;                 // o in q-slot

    const int i0 = blockIdx.x * 128;
    const int tid = threadIdx.x, w = tid >> 6, l = tid & 63;
    const int lr = l & 15, lq = l >> 4;
    const int srow = l >> 2, scol8 = (l & 3) * 8;
    const int kp = tid >> 4, dq = tid & 15;   // j-pair, d-quad
    const int kcol = ((((kp >> 2) ^ ((dq >> 1) & 3)) << 3) | ((kp & 3) << 1));

    f32x4 acc[2][4];
#pragma unroll
    for (int i = 0; i < 2; i++)
#pragma unroll
        for (int j = 0; j < 4; j++)
#pragma unroll
            for (int r = 0; r < 4; r++) acc[i][j][r] = 0.f;

    bf16* Al = As + w * 1024;
    unsigned short* Bw = (unsigned short*)Bst;

    for (int k0 = 0; k0 < 512; k0 += 32) {
        const bf16* Ag = Ab + (long)(i0 + w * 32) * 512 + k0;
        g2l16(Ag + (long)srow * 512 + scol8,        Al);
        g2l16(Ag + (long)(srow + 16) * 512 + scol8, Al + 512);

        const bf16* Bg = Bb + (long)(k0 + 2 * kp) * 2304 + dq * 4;
        ushort4v u0 = *(const ushort4v*)(Bg);
        ushort4v u1 = *(const ushort4v*)(Bg + 2304);
#pragma unroll
        for (int r = 0; r < 4; r++) {
            unsigned p = (unsigned)u0[r] | ((unsigned)u1[r] << 16);
            *(unsigned*)(Bw + (dq * 4 + r) * 40 + kcol) = p;
        }
        __syncthreads();

        bf16x8 fa[2], fb[4];
#pragma unroll
        for (int i = 0; i < 2; i++)
            fa[i] = *(const bf16x8*)(As + (w * 32 + i * 16 + lr) * 32 + lq * 8);
#pragma unroll
        for (int i = 0; i < 4; i++) {
            const int d = i * 16 + lr;
            fb[i] = *(const bf16x8*)(Bst + d * 40 + ((lq ^ ((d >> 3) & 3)) << 3));
        }
#pragma unroll
        for (int mi = 0; mi < 2; mi++)
#pragma unroll
            for (int ni = 0; ni < 4; ni++)
                acc[mi][ni] = __builtin_amdgcn_mfma_f32_16x16x32_bf16(
                    fa[mi], fb[ni], acc[mi][ni], 0, 0, 0);
        __syncthreads();
    }

#pragma unroll
    for (int ni = 0; ni < 4; ni++) {
        const int gc = ni * 16 + lr;
#pragma unroll
        for (int mi = 0; mi < 2; mi++)
#pragma unroll
            for (int r = 0; r < 4; r++) {
                const int gr = i0 + w * 32 + mi * 16 + lq * 4 + r;
                Cb[(long)gr * 2304 + gc] = (bf16)acc[mi][ni][r];
            }
    }
}

// ---------------------------------------------------------------------------
// transpose+convert: in f32 [K,N] -> out bf16 [N,K].  32x32 tiles.
// ---------------------------------------------------------------------------
__global__ __launch_bounds__(256)
void tconv_k(const float* __restrict__ in, bf16* __restrict__ out,
             int K, int N)
{
    __shared__ float t[32][33];
    const int n0 = blockIdx.x * 32, k0 = blockIdx.y * 32;
    const int x = threadIdx.x, y = threadIdx.y;
#pragma unroll
    for (int yy = 0; yy < 4; yy++)
        t[y + yy * 8][x] = in[(long)(k0 + y + yy * 8) * N + n0 + x];
    __syncthreads();
#pragma unroll
    for (int yy = 0; yy < 4; yy++)
        out[(long)(n0 + y + yy * 8) * K + k0 + x] = (bf16)t[x][y + yy * 8];
}

// ---------------------------------------------------------------------------
// Fused residual-reduce + LayerNorm.
// ---------------------------------------------------------------------------
__global__ __launch_bounds__(256)
void lnres_k(float* __restrict__ xf, const bf16* __restrict__ P0,
             const bf16* __restrict__ P1, const float* __restrict__ bias,
             const float* __restrict__ gam, bf16* __restrict__ out)
{
    const int row = blockIdx.x, t = threadIdx.x;
    float* xr = xf + (long)row * 768;
    float v[3];
#pragma unroll
    for (int i = 0; i < 3; i++) {
        const int c = t + i * 256;
        float xv = xr[c];
        if (P0) {
            xv += LSCALE * ((float)P0[(long)row * 768 + c] +
                            (float)P1[(long)row * 768 + c] + bias[c]);
            xr[c] = xv;
        }
        v[i] = xv;
    }
    float s  = v[0] + v[1] + v[2];
    float ss = v[0] * v[0] + v[1] * v[1] + v[2] * v[2];
#pragma unroll
    for (int off = 32; off; off >>= 1) {
        s  += __shfl_xor(s, off);
        ss += __shfl_xor(ss, off);
    }
    __shared__ float ps[4], pss[4];
    const int wv = t >> 6, l = t & 63;
    if (l == 0) { ps[wv] = s; pss[wv] = ss; }
    __syncthreads();
    s  = ps[0] + ps[1] + ps[2] + ps[3];
    ss = pss[0] + pss[1] + pss[2] + pss[3];
    const float mu = s * (1.f / 768.f);
    const float rs = rsqrtf(ss * (1.f / 768.f) - mu * mu + 1e-5f);
    bf16* orow = out + (long)row * 768;
#pragma unroll
    for (int i = 0; i < 3; i++) {
        const int c = t + i * 256;
        orow[c] = (bf16)((v[i] - mu) * rs * gam[c]);
    }
}

// final: d_out = xf + LS*(P0 + P1 + bias)   (f32 out)
__global__ __launch_bounds__(256)
void outres_k(const float* __restrict__ xf, const bf16* __restrict__ P0,
              const bf16* __restrict__ P1, const float* __restrict__ bias,
              float* __restrict__ out)
{
    const long i = (long)blockIdx.x * 256 + threadIdx.x;
    const int c = (int)(i % 768);
    out[i] = xf[i] + LSCALE * ((float)P0[i] + (float)P1[i] + bias[c]);
}

// ---------------------------------------------------------------------------
// talking-heads mix (pre) -> softmax -> mix (post), in place on S chunk
// [4,12,512,512]. one block per (b-in-chunk, i); thread owns j-pair (2t,2t+1).
// ---------------------------------------------------------------------------
__global__ __launch_bounds__(256)
void mixsm_k(bf16* __restrict__ S, const float* __restrict__ mp,
             const float* __restrict__ mq)
{
    __shared__ float buf[12][512];
    __shared__ float rds[12];
    const int b = blockIdx.y, i = blockIdx.x, t = threadIdx.x;
    bf16* Sb = S + ((long)b * 12 * 512 + i) * 512;

    float s0[12], s1[12];
#pragma unroll
    for (int h = 0; h < 12; h++) {
        union { unsigned u; bf16 v[2]; } p;
        p.u = *(const unsigned*)(Sb + (long)h * 262144 + 2 * t);
        s0[h] = (float)p.v[0];
        s1[h] = (float)p.v[1];
    }
#pragma unroll
    for (int g = 0; g < 12; g++) {
        float a0 = 0.f, a1 = 0.f;
#pragma unroll
        for (int h = 0; h < 12; h++) {
            const float m = mp[h * 12 + g];     // uniform -> SGPR
            a0 += s0[h] * m;
            a1 += s1[h] * m;
        }
        *(float2*)(&buf[g][2 * t]) = make_float2(a0, a1);
    }
    __syncthreads();

    const int wv = t >> 6, l = t & 63;
    for (int g = wv; g < 12; g += 4) {
        float mx = -3.0e38f;
#pragma unroll
        for (int k = 0; k < 8; k++) mx = fmaxf(mx, buf[g][l + 64 * k]);
#pragma unroll
        for (int off = 32; off; off >>= 1) mx = fmaxf(mx, __shfl_xor(mx, off));
        float sm = 0.f;
#pragma unroll
        for (int k = 0; k < 8; k++) {
            const float e = __expf(buf[g][l + 64 * k] - mx);
            buf[g][l + 64 * k] = e;
            sm += e;
        }
#pragma unroll
        for (int off = 32; off; off >>= 1) sm += __shfl_xor(sm, off);
        if (l == 0) rds[g] = 1.f / sm;
    }
    __syncthreads();

    float e0[12], e1[12];
#pragma unroll
    for (int h = 0; h < 12; h++) {
        const float2 ee = *(const float2*)(&buf[h][2 * t]);
        const float rd = rds[h];
        e0[h] = ee.x * rd;
        e1[h] = ee.y * rd;
    }
#pragma unroll
    for (int g = 0; g < 12; g++) {
        float a0 = 0.f, a1 = 0.f;
#pragma unroll
        for (int h = 0; h < 12; h++) {
            const float m = mq[h * 12 + g];     // uniform -> SGPR
            a0 += e0[h] * m;
            a1 += e1[h] * m;
        }
        union { unsigned u; bf16 v[2]; } p;
        p.v[0] = (bf16)a0;
        p.v[1] = (bf16)a1;
        *(unsigned*)(Sb + (long)g * 262144 + 2 * t) = p.u;
    }
}

// ---------------------------------------------------------------------------
extern "C" void kernel_launch(void* const* d_in, const int* in_sizes, int n_in,
                              void* d_out, int out_size, void* d_ws, size_t ws_size,
                              hipStream_t stream)
{
    (void)in_sizes; (void)n_in; (void)out_size; (void)ws_size;
    const float* x   = (const float*)d_in[0];
    const float* ln1 = (const float*)d_in[1];
    const float* Wq  = (const float*)d_in[2];
    const float* Wkv = (const float*)d_in[3];
    const float* mp  = (const float*)d_in[4];
    const float* mq  = (const float*)d_in[5];
    const float* Wo  = (const float*)d_in[6];
    const float* bo  = (const float*)d_in[7];
    const float* ln2 = (const float*)d_in[8];
    const float* W1  = (const float*)d_in[9];
    const float* b1  = (const float*)d_in[10];
    const float* W2  = (const float*)d_in[11];
    const float* b2  = (const float*)d_in[12];

    char* ws = (char*)d_ws;
    float* xf  = (float*)(ws);               // [4096,768] f32
    bf16* h    = (bf16*)(ws + 12582912);     // [4096,768]; partial plane P0
    bf16* qkv  = (bf16*)(ws + 18874368);     // [4096,2304]; o in q-slot; P1(W2)
    bf16* S    = (bf16*)(ws + 37748736);     // [48,512,512]; MLP mid; P1(Wo)
    bf16* Wt   = (bf16*)(ws + 62914560);     // transposed bf16 weight
    bf16* mid  = S;
    bf16* P0   = h;
    bf16* P1w2 = qkv;
    bf16* P1wo = S;
    const long P1W2_OFF = 3145728;           // (qkv - h) in elements
    const long P1WO_OFF = 12582912;          // (S - h) in elements

    const dim3 tb(32, 8);

    hipMemcpyAsync(xf, x, 4096 * 768 * sizeof(float),
                   hipMemcpyDeviceToDevice, stream);

    for (int L = 0; L < 4; L++) {
        tconv_k<<<dim3(24, 24), tb, 0, stream>>>(Wq + (long)L * 589824, Wt, 768, 768);
        tconv_k<<<dim3(48, 24), tb, 0, stream>>>(Wkv + (long)L * 1179648, Wt + 589824, 768, 1536);

        // x += LS*(prev-W2 partials + b2_{L-1}) [L>0]; h = LN(x)*ln1
        if (L == 0)
            lnres_k<<<4096, 256, 0, stream>>>(xf, nullptr, nullptr, nullptr,
                                              ln1 + L * 768, h);
        else
            lnres_k<<<4096, 256, 0, stream>>>(xf, P0, P1w2, b2 + (L - 1) * 768,
                                              ln1 + L * 768, h);

        // qkv = h @ [Wq | Wkv]
        gemm_bt<0><<<dim3(32, 18, 1), 256, 0, stream>>>(
            h, 768, 0, 0, Wt, 768, 0, 0,
            qkv, 2304, 0, 0, 4096, 2304, 768, 1, nullptr, 1.f);

        // attention in 2 chunks of 4 batches
        for (int c = 0; c < 2; c++) {
            const long qb = (long)c * 4718592;
            gemm_bt<0><<<dim3(4, 4, 48), 256, 0, stream>>>(
                qkv + qb,       2304, 1179648, 64,
                qkv + 768 + qb, 2304, 1179648, 64,
                S,               512, 3145728, 262144,
                512, 512, 64, 12, nullptr, 0.125f);

            mixsm_k<<<dim3(512, 4), 256, 0, stream>>>(S, mp + L * 144, mq + L * 144);

            // o (q-slot of this chunk) = attn @ v
            gemm_av<<<dim3(4, 48), 256, 0, stream>>>(S, qkv + qb, qkv + qb);
        }

        // Wo partials: P0/P1wo = o @ Wo (split-K=2)
        tconv_k<<<dim3(24, 24), tb, 0, stream>>>(Wo + (long)L * 589824, Wt, 768, 768);
        gemm_bt<4><<<dim3(32, 6, 2), 256, 0, stream>>>(
            qkv, 2304, 0, 384, Wt, 768, 0, 384,
            P0, 768, 0, P1WO_OFF, 4096, 768, 384, 2, nullptr, 1.f);

        // x += LS*(P0+P1+bo); h = LN(x)*ln2
        lnres_k<<<4096, 256, 0, stream>>>(xf, P0, P1wo, bo + L * 768,
                                          ln2 + L * 768, h);

        // mid = gelu(h @ W1 + b1)
        tconv_k<<<dim3(96, 24), tb, 0, stream>>>(W1 + (long)L * 2359296, Wt, 768, 3072);
        gemm_bt<1><<<dim3(32, 24, 1), 256, 0, stream>>>(
            h, 768, 0, 0, Wt, 768, 0, 0,
            mid, 3072, 0, 0, 4096, 3072, 768, 1, b1 + L * 3072, 1.f);

        // W2 partials: P0/P1w2 = mid @ W2 (split-K=2)
        tconv_k<<<dim3(24, 96), tb, 0, stream>>>(W2 + (long)L * 2359296, Wt, 3072, 768);
        gemm_bt<4><<<dim3(32, 6, 2), 256, 0, stream>>>(
            mid, 3072, 0, 1536, Wt, 3072, 0, 1536,
            P0, 768, 0, P1W2_OFF, 4096, 768, 1536, 2, nullptr, 1.f);
    }

    // d_out = xf + LS*(P0+P1+b2_3)
    outres_k<<<12288, 256, 0, stream>>>(xf, P0, P1w2, b2 + 3 * 768, (float*)d_out);
}